// Round 6
// baseline (3906.576 us; speedup 1.0000x reference)
//
#include <hip/hip_runtime.h>

// RGCN 3-layer forward, MI355X — decoupled aggregate-then-transform.
// Identity: sum_e x[src_e] @ W_r == (sum_e x[src_e]) @ W_r.
// Round-5 lesson: fusing aggregation+GEMM in one block serializes tiny edge lists
// between barriers -> latency-bound (VALU 2%). So: (1) standalone edge-parallel
// aggregation kernel (6252 independent blocks, LDS fp32 tile + ds atomics,
// prefetch-pipelined) writes Y_r bf16 [4][N][128] from L3-hot x; (2) barrier-free
// zero-LDS big-K GEMM (K=640: x@Wroot + sum Y_r@W_r) with A direct from stream,
// B from L2-hot wt. 2 passes x 4 relations (bf16 partial) keep Y L3-resident and
// workspace ~186 MB. Edges bucket-sorted by (rel, dst_tile64) once (cheap).

#define DEVI __device__ __forceinline__

typedef __attribute__((ext_vector_type(8))) short bf16x8;
typedef __attribute__((ext_vector_type(4))) float f32x4;

DEVI unsigned short f2b(float f) {
  unsigned int u = __builtin_bit_cast(unsigned int, f);
  unsigned int r = (u + 0x7FFFu + ((u >> 16) & 1u)) >> 16;
  return (unsigned short)r;
}
DEVI float b2f(unsigned short h) {
  unsigned int u = ((unsigned int)h) << 16;
  return __builtin_bit_cast(float, u);
}

// ---------------- bucket sort by key = rel*NT + (dst>>6) ----------------

__global__ void k_zero2(int* __restrict__ cnt, int n) {
  int stride = gridDim.x * blockDim.x;
  for (int i = blockIdx.x * blockDim.x + threadIdx.x; i < n; i += stride) cnt[i] = 0;
}

__global__ void k_hist2(const int* __restrict__ et, const int* __restrict__ edst,
                        int* __restrict__ cnt, int NT, int E) {
  int stride = gridDim.x * blockDim.x;
  for (int i = blockIdx.x * blockDim.x + threadIdx.x; i < E; i += stride)
    atomicAdd(&cnt[(et[i] & 7) * NT + (edst[i] >> 6)], 1);
}

__global__ void k_scan1(const int* __restrict__ cnt, int* __restrict__ offs,
                        int* __restrict__ bsum, int KT) {
  __shared__ int l[256];
  int g = blockIdx.x * 256 + threadIdx.x;
  int v = (g < KT) ? cnt[g] : 0;
  l[threadIdx.x] = v;
  __syncthreads();
  for (int o = 1; o < 256; o <<= 1) {
    int t = (threadIdx.x >= o) ? l[threadIdx.x - o] : 0;
    __syncthreads();
    l[threadIdx.x] += t;
    __syncthreads();
  }
  if (g < KT) offs[g] = l[threadIdx.x] - v;
  if (threadIdx.x == 255) bsum[blockIdx.x] = l[255];
}

__global__ void k_scan2(int* __restrict__ bsum, int nb) {
  __shared__ int l[256];
  __shared__ int carry;
  if (threadIdx.x == 0) carry = 0;
  __syncthreads();
  for (int base = 0; base < nb; base += 256) {
    int g = base + threadIdx.x;
    int v = (g < nb) ? bsum[g] : 0;
    l[threadIdx.x] = v;
    __syncthreads();
    for (int o = 1; o < 256; o <<= 1) {
      int t = (threadIdx.x >= o) ? l[threadIdx.x - o] : 0;
      __syncthreads();
      l[threadIdx.x] += t;
      __syncthreads();
    }
    if (g < nb) bsum[g] = l[threadIdx.x] - v + carry;
    __syncthreads();
    if (threadIdx.x == 0) carry += l[255];
    __syncthreads();
  }
}

__global__ void k_scan3(int* __restrict__ offs, const int* __restrict__ bsum,
                        int* __restrict__ cursor, int KT, int E) {
  int g = blockIdx.x * 256 + threadIdx.x;
  if (g < KT) {
    int v = offs[g] + bsum[blockIdx.x];
    offs[g] = v;
    cursor[g] = v;
  }
  if (g == 0) offs[KT] = E;
}

__global__ void k_fill2(const int* __restrict__ et, const int* __restrict__ esrc,
                        const int* __restrict__ edst, int* __restrict__ cursor,
                        int* __restrict__ packed, int NT, int E) {
  int stride = gridDim.x * blockDim.x;
  for (int i = blockIdx.x * blockDim.x + threadIdx.x; i < E; i += stride) {
    int d = edst[i];
    int key = (et[i] & 7) * NT + (d >> 6);
    int pos = atomicAdd(&cursor[key], 1);
    packed[pos] = ((d & 63) << 20) | esrc[i];
  }
}

// ---------------- weight prep: fp32 [9][128][DOUT] -> bf16 transposed [9][DOUT][128] ----------------

__global__ void wprep_kernel(const float* __restrict__ Wrel, const float* __restrict__ Wroot,
                             unsigned short* __restrict__ wt, int DOUT) {
  int total = 9 * 128 * DOUT;
  int stride = gridDim.x * blockDim.x;
  for (int i = blockIdx.x * blockDim.x + threadIdx.x; i < total; i += stride) {
    int k = i & 127;
    int oo = i >> 7;           // rr*DOUT + o
    int o = oo % DOUT;
    int rr = oo / DOUT;
    float v = (rr < 8) ? Wrel[((size_t)rr * 128 + k) * DOUT + o]
                       : Wroot[(size_t)k * DOUT + o];
    wt[i] = f2b(v);
  }
}

// ---------------- aggregation: Y[rg][tile rows] = sum_{e in bucket} x[src_e] ----------------
// grid = (NT, 4); block = 256. Quarter-wave per edge, prefetch-pipelined.

__launch_bounds__(256)
__global__ void agg_kernel(const unsigned short* __restrict__ xb,   // [N][128] bf16
                           const int* __restrict__ boffs,           // [8*NT+1]
                           const int* __restrict__ packed,          // [E] row<<20|src
                           unsigned short* __restrict__ Y,          // [4][NTr][128]
                           int r0, int NT, int NTr) {
  __shared__ float yl[64 * 132];

  int tile = blockIdx.x, rg = blockIdx.y;
  int tid = threadIdx.x, wid = tid >> 6, lane = tid & 63;
  int colb = lane & 15;

#pragma unroll 4
  for (int i = tid; i < 64 * 132 / 4; i += 256) {
    f32x4 z = {0.f, 0.f, 0.f, 0.f};
    ((f32x4*)yl)[i] = z;
  }
  __syncthreads();

  int bkt = (r0 + rg) * NT + tile;
  int lo = boffs[bkt], hi = boffs[bkt + 1];
  int sub = wid * 4 + (lane >> 4);           // quarter-wave id 0..15

  int i = lo + sub;
  int pk = 0;
  bf16x8 v{};
  if (i < hi) {
    pk = packed[i];
    v = *(const bf16x8*)(xb + (size_t)(pk & 0xFFFFF) * 128 + colb * 8);
  }
  while (i < hi) {
    int ni = i + 16;
    int npk = 0;
    bf16x8 nv{};
    if (ni < hi) {
      npk = packed[ni];
      nv = *(const bf16x8*)(xb + (size_t)(npk & 0xFFFFF) * 128 + colb * 8);
    }
    float* yr = yl + (pk >> 20) * 132 + colb * 8;
#pragma unroll
    for (int c = 0; c < 8; ++c)
      atomicAdd(&yr[c], b2f((unsigned short)v[c]));
    i = ni; pk = npk; v = nv;
  }
  __syncthreads();

  // write 64x128 bf16 tile (4096 dwords), coalesced
  unsigned* Yd = (unsigned*)(Y + ((size_t)rg * NTr + (size_t)tile * 64) * 128);
  for (int idx = tid; idx < 4096; idx += 256) {
    int row = idx >> 6, c = idx & 63;
    float f0 = yl[row * 132 + c * 2];
    float f1 = yl[row * 132 + c * 2 + 1];
    Yd[idx] = (unsigned)f2b(f0) | ((unsigned)f2b(f1) << 16);
  }
}

// ---------------- big-K GEMM: acc = sum_t A_t @ W_t ; zero LDS, no barriers ----------------

struct KTiles { const unsigned short* a[5]; const unsigned short* w[5]; };

// EPI: 0 = +bias -> bf16 partial; 1 = +partial, relu -> bf16; 2 = +partial, log-softmax -> f32
template <int DOUT, int NK, int EPI>
__launch_bounds__(256)
__global__ void gemm_big(KTiles kt, const float* __restrict__ bias,
                         const unsigned short* __restrict__ partial,
                         unsigned short* __restrict__ out_b,
                         float* __restrict__ out_f, int N) {
  int tid = threadIdx.x, wid = tid >> 6, lane = tid & 63;
  int colb = lane & 15, kgrp = lane >> 4;
  int rowbase = blockIdx.x * 128 + wid * 32;

  f32x4 acc[2][DOUT / 16];
#pragma unroll
  for (int t = 0; t < 2; ++t)
#pragma unroll
    for (int nf = 0; nf < DOUT / 16; ++nf) {
      f32x4 z = {0.f, 0.f, 0.f, 0.f};
      acc[t][nf] = z;
    }

  int ra = rowbase + colb, rb = ra + 16;
  size_t oa = (size_t)(ra < N ? ra : 0) * 128;
  size_t ob = (size_t)(rb < N ? rb : 0) * 128;

#pragma unroll
  for (int t = 0; t < NK; ++t) {
    const unsigned short* A = kt.a[t];
    const unsigned short* W = kt.w[t];
#pragma unroll
    for (int kk = 0; kk < 4; ++kk) {
      int kbase = kk * 32 + kgrp * 8;
      bf16x8 a0 = *(const bf16x8*)(A + oa + kbase);
      bf16x8 a1 = *(const bf16x8*)(A + ob + kbase);
#pragma unroll
      for (int nf = 0; nf < DOUT / 16; ++nf) {
        bf16x8 b = *(const bf16x8*)(W + (size_t)(nf * 16 + colb) * 128 + kbase);
        acc[0][nf] = __builtin_amdgcn_mfma_f32_16x16x32_bf16(a0, b, acc[0][nf], 0, 0, 0);
        acc[1][nf] = __builtin_amdgcn_mfma_f32_16x16x32_bf16(a1, b, acc[1][nf], 0, 0, 0);
      }
    }
  }

  float bv[DOUT / 16];
  if (EPI == 0) {
#pragma unroll
    for (int nf = 0; nf < DOUT / 16; ++nf) bv[nf] = bias[nf * 16 + colb];
  }

#pragma unroll
  for (int t = 0; t < 2; ++t) {
#pragma unroll
    for (int i = 0; i < 4; ++i) {
      int row = rowbase + t * 16 + kgrp * 4 + i;
      if (row >= N) continue;
      if (EPI == 0) {
#pragma unroll
        for (int nf = 0; nf < DOUT / 16; ++nf)
          out_b[(size_t)row * DOUT + nf * 16 + colb] = f2b(acc[t][nf][i] + bv[nf]);
      } else if (EPI == 1) {
#pragma unroll
        for (int nf = 0; nf < DOUT / 16; ++nf) {
          int col = nf * 16 + colb;
          float v = acc[t][nf][i] + b2f(partial[(size_t)row * DOUT + col]);
          out_b[(size_t)row * DOUT + col] = f2b(fmaxf(v, 0.f));
        }
      } else {
        // DOUT==64 log-softmax: row's 64 cols live in this 16-lane group
        float v[4];
#pragma unroll
        for (int nf = 0; nf < 4; ++nf)
          v[nf] = acc[t][nf][i] + b2f(partial[(size_t)row * 64 + nf * 16 + colb]);
        float m = fmaxf(fmaxf(v[0], v[1]), fmaxf(v[2], v[3]));
#pragma unroll
        for (int s = 1; s < 16; s <<= 1) m = fmaxf(m, __shfl_xor(m, s));
        float sum = 0.f;
#pragma unroll
        for (int nf = 0; nf < 4; ++nf) sum += __expf(v[nf] - m);
#pragma unroll
        for (int s = 1; s < 16; s <<= 1) sum += __shfl_xor(sum, s);
        float lse = m + __logf(sum);
#pragma unroll
        for (int nf = 0; nf < 4; ++nf)
          out_f[(size_t)row * 64 + nf * 16 + colb] = v[nf] - lse;
      }
    }
  }
}

// ---------------- input cast ----------------

__global__ void cast_kernel(const float* __restrict__ in, unsigned short* __restrict__ out,
                            int n4) {
  int stride = gridDim.x * blockDim.x;
  for (int i = blockIdx.x * blockDim.x + threadIdx.x; i < n4; i += stride) {
    float4 v = ((const float4*)in)[i];
    ushort4 o;
    o.x = f2b(v.x); o.y = f2b(v.y); o.z = f2b(v.z); o.w = f2b(v.w);
    ((ushort4*)out)[i] = o;
  }
}

// ---------------- launch ----------------

extern "C" void kernel_launch(void* const* d_in, const int* in_sizes, int n_in,
                              void* d_out, int out_size, void* d_ws, size_t ws_size,
                              hipStream_t stream) {
  const float* x = (const float*)d_in[0];
  const int* eidx = (const int*)d_in[1];     // int32
  const int* et = (const int*)d_in[2];       // int32
  const float* Wrel1 = (const float*)d_in[3];
  const float* Wroot1 = (const float*)d_in[4];
  const float* b1 = (const float*)d_in[5];
  const float* Wrel2 = (const float*)d_in[6];
  const float* Wroot2 = (const float*)d_in[7];
  const float* b2 = (const float*)d_in[8];
  const float* Wrel3 = (const float*)d_in[9];
  const float* Wroot3 = (const float*)d_in[10];
  const float* b3 = (const float*)d_in[11];

  const int N = in_sizes[0] / 128;    // 100000
  const int E = in_sizes[2];          // 1600000
  const int NT = (N + 63) / 64;       // 1563 dst tiles
  const int NTr = NT * 64;            // padded row count
  const int NB = 8 * NT;              // 12504 buckets
  const int* esrc = eidx;
  const int* edst = eidx + E;

  char* p = (char*)d_ws;
  auto carve = [&](size_t bytes) {
    void* q = (void*)p;
    p += (bytes + 255) & ~(size_t)255;
    return q;
  };
  unsigned short* bufX0 = (unsigned short*)carve((size_t)NTr * 128 * 2);   // 25.6 MB
  unsigned short* bufX1 = (unsigned short*)carve((size_t)NTr * 128 * 2);   // 25.6 MB
  unsigned short* part = (unsigned short*)carve((size_t)NTr * 128 * 2);    // 25.6 MB bf16 partial
  unsigned short* wt1 = (unsigned short*)carve((size_t)9 * 128 * 128 * 2);
  unsigned short* wt2 = (unsigned short*)carve((size_t)9 * 128 * 128 * 2);
  unsigned short* wt3 = (unsigned short*)carve((size_t)9 * 64 * 128 * 2);
  int* packed = (int*)carve((size_t)E * 4);
  int* cnt = (int*)carve((size_t)NB * 4);
  int* offs = (int*)carve((size_t)(NB + 1) * 4);
  int* cursor = (int*)carve((size_t)NB * 4);
  const int nbs = (NB + 255) / 256;
  int* bsum = (int*)carve((size_t)nbs * 4);
  unsigned short* Y = (unsigned short*)carve((size_t)4 * NTr * 128 * 2);   // 102.4 MB

  // ---- bucket sort (once; reused by all 3 layers) ----
  k_zero2<<<64, 256, 0, stream>>>(cnt, NB);
  k_hist2<<<2048, 256, 0, stream>>>(et, edst, cnt, NT, E);
  k_scan1<<<nbs, 256, 0, stream>>>(cnt, offs, bsum, NB);
  k_scan2<<<1, 256, 0, stream>>>(bsum, nbs);
  k_scan3<<<nbs, 256, 0, stream>>>(offs, bsum, cursor, NB, E);
  k_fill2<<<2048, 256, 0, stream>>>(et, esrc, edst, cursor, packed, NT, E);

  // ---- weight prep + input cast ----
  wprep_kernel<<<576, 256, 0, stream>>>(Wrel1, Wroot1, wt1, 128);
  wprep_kernel<<<576, 256, 0, stream>>>(Wrel2, Wroot2, wt2, 128);
  wprep_kernel<<<288, 256, 0, stream>>>(Wrel3, Wroot3, wt3, 64);
  cast_kernel<<<2048, 256, 0, stream>>>(x, bufX0, N * 128 / 4);

  const int gblk = (NTr + 127) / 128;
  const dim3 aggGrid(NT, 4);
  const size_t Ystep = (size_t)NTr * 128;

  auto layer128 = [&](const unsigned short* xin, const unsigned short* wt,
                      const float* bias, unsigned short* xout) {
    agg_kernel<<<aggGrid, 256, 0, stream>>>(xin, offs, packed, Y, 0, NT, NTr);
    KTiles kt1;
    kt1.a[0] = xin;            kt1.w[0] = wt + (size_t)8 * 128 * 128;
    for (int j = 0; j < 4; ++j) { kt1.a[j + 1] = Y + Ystep * j; kt1.w[j + 1] = wt + (size_t)j * 128 * 128; }
    gemm_big<128, 5, 0><<<gblk, 256, 0, stream>>>(kt1, bias, (const unsigned short*)nullptr, part, (float*)nullptr, N);
    agg_kernel<<<aggGrid, 256, 0, stream>>>(xin, offs, packed, Y, 4, NT, NTr);
    KTiles kt2;
    for (int j = 0; j < 4; ++j) { kt2.a[j] = Y + Ystep * j; kt2.w[j] = wt + (size_t)(4 + j) * 128 * 128; }
    kt2.a[4] = kt2.a[0]; kt2.w[4] = kt2.w[0];
    gemm_big<128, 4, 1><<<gblk, 256, 0, stream>>>(kt2, (const float*)nullptr, part, xout, (float*)nullptr, N);
  };

  layer128(bufX0, wt1, b1, bufX1);
  layer128(bufX1, wt2, b2, bufX0);

  // ---- layer 3 (128 -> 64, fused log-softmax) ----
  agg_kernel<<<aggGrid, 256, 0, stream>>>(bufX0, offs, packed, Y, 0, NT, NTr);
  KTiles kt1;
  kt1.a[0] = bufX0;           kt1.w[0] = wt3 + (size_t)8 * 64 * 128;
  for (int j = 0; j < 4; ++j) { kt1.a[j + 1] = Y + Ystep * j; kt1.w[j + 1] = wt3 + (size_t)j * 64 * 128; }
  gemm_big<64, 5, 0><<<gblk, 256, 0, stream>>>(kt1, b3, (const unsigned short*)nullptr, part, (float*)nullptr, N);
  agg_kernel<<<aggGrid, 256, 0, stream>>>(bufX0, offs, packed, Y, 4, NT, NTr);
  KTiles kt2;
  for (int j = 0; j < 4; ++j) { kt2.a[j] = Y + Ystep * j; kt2.w[j] = wt3 + (size_t)(4 + j) * 64 * 128; }
  kt2.a[4] = kt2.a[0]; kt2.w[4] = kt2.w[0];
  gemm_big<64, 4, 2><<<gblk, 256, 0, stream>>>(kt2, (const float*)nullptr, part, (unsigned short*)nullptr, (float*)d_out, N);
}

// Round 7
// 1221.269 us; speedup vs baseline: 3.1988x; 3.1988x over previous
//
#include <hip/hip_runtime.h>

// RGCN 3-layer forward, MI355X — decoupled aggregate-then-transform, v2.
// Identity: sum_e x[src_e] @ W_r == (sum_e x[src_e]) @ W_r.
// Round-6 lesson: LDS-tiled aggregation caps occupancy (4 blk/CU, 16 waves) ->
// latency-bound at 3.6% VALU. Round-3's gather hid the same latency with 100k
// waves, no LDS, no barriers. So: bucket sort by (rel,dst_tile64) [cheap, few
// keys] + per-bucket counting sort by row (k_seg, coalesced, no global random
// atomics) -> per-(rel,dst) segments; aggregation = 1 wave per dst row x 4 rels,
// zero LDS, 4-batched coalesced 256B row loads from L3-hot x, writes Y_r bf16.
// Then barrier-free zero-LDS big-K GEMM (K=640: x@Wroot + sum Y_r@W_r), 2 passes
// of 4 rels (bf16 partial); epilogues fuse bias/ReLU/log-softmax.

#define DEVI __device__ __forceinline__

typedef __attribute__((ext_vector_type(8))) short bf16x8;
typedef __attribute__((ext_vector_type(4))) float f32x4;

DEVI unsigned short f2b(float f) {
  unsigned int u = __builtin_bit_cast(unsigned int, f);
  unsigned int r = (u + 0x7FFFu + ((u >> 16) & 1u)) >> 16;
  return (unsigned short)r;
}
DEVI float b2f(unsigned short h) {
  unsigned int u = ((unsigned int)h) << 16;
  return __builtin_bit_cast(float, u);
}

// ---------------- bucket sort by key = rel*NT + (dst>>6) ----------------

__global__ void k_zero2(int* __restrict__ cnt, int n) {
  int stride = gridDim.x * blockDim.x;
  for (int i = blockIdx.x * blockDim.x + threadIdx.x; i < n; i += stride) cnt[i] = 0;
}

__global__ void k_hist2(const int* __restrict__ et, const int* __restrict__ edst,
                        int* __restrict__ cnt, int NT, int E) {
  int stride = gridDim.x * blockDim.x;
  for (int i = blockIdx.x * blockDim.x + threadIdx.x; i < E; i += stride)
    atomicAdd(&cnt[(et[i] & 7) * NT + (edst[i] >> 6)], 1);
}

__global__ void k_scan1(const int* __restrict__ cnt, int* __restrict__ offs,
                        int* __restrict__ bsum, int KT) {
  __shared__ int l[256];
  int g = blockIdx.x * 256 + threadIdx.x;
  int v = (g < KT) ? cnt[g] : 0;
  l[threadIdx.x] = v;
  __syncthreads();
  for (int o = 1; o < 256; o <<= 1) {
    int t = (threadIdx.x >= o) ? l[threadIdx.x - o] : 0;
    __syncthreads();
    l[threadIdx.x] += t;
    __syncthreads();
  }
  if (g < KT) offs[g] = l[threadIdx.x] - v;
  if (threadIdx.x == 255) bsum[blockIdx.x] = l[255];
}

__global__ void k_scan2(int* __restrict__ bsum, int nb) {
  __shared__ int l[256];
  __shared__ int carry;
  if (threadIdx.x == 0) carry = 0;
  __syncthreads();
  for (int base = 0; base < nb; base += 256) {
    int g = base + threadIdx.x;
    int v = (g < nb) ? bsum[g] : 0;
    l[threadIdx.x] = v;
    __syncthreads();
    for (int o = 1; o < 256; o <<= 1) {
      int t = (threadIdx.x >= o) ? l[threadIdx.x - o] : 0;
      __syncthreads();
      l[threadIdx.x] += t;
      __syncthreads();
    }
    if (g < nb) bsum[g] = l[threadIdx.x] - v + carry;
    __syncthreads();
    if (threadIdx.x == 0) carry += l[255];
    __syncthreads();
  }
}

__global__ void k_scan3(int* __restrict__ offs, const int* __restrict__ bsum,
                        int* __restrict__ cursor, int KT, int E) {
  int g = blockIdx.x * 256 + threadIdx.x;
  if (g < KT) {
    int v = offs[g] + bsum[blockIdx.x];
    offs[g] = v;
    cursor[g] = v;
  }
  if (g == 0) offs[KT] = E;
}

__global__ void k_fill2(const int* __restrict__ et, const int* __restrict__ esrc,
                        const int* __restrict__ edst, int* __restrict__ cursor,
                        int* __restrict__ packed, int NT, int E) {
  int stride = gridDim.x * blockDim.x;
  for (int i = blockIdx.x * blockDim.x + threadIdx.x; i < E; i += stride) {
    int d = edst[i];
    int key = (et[i] & 7) * NT + (d >> 6);
    int pos = atomicAdd(&cursor[key], 1);
    packed[pos] = ((d & 63) << 20) | esrc[i];
  }
}

// ---------------- per-bucket counting sort by row -> per-(rel,dst) segments ----
// block = 64 threads = 1 wave, one bucket each. Output: srcl (src only) grouped
// by row within bucket, segoffs[b*64+r] = start of (bucket b, row r).

__global__ void k_seg(const int* __restrict__ boffs, const int* __restrict__ pin,
                      int* __restrict__ srcl, int* __restrict__ segoffs,
                      int NB, int E) {
  __shared__ int rc[64], sc[64], rcur[64];
  int b = blockIdx.x;
  int lo = boffs[b], hi = boffs[b + 1], n = hi - lo;
  int t = threadIdx.x;
  rc[t] = 0;
  __syncthreads();
  for (int i = t; i < n; i += 64) atomicAdd(&rc[pin[lo + i] >> 20], 1);
  __syncthreads();
  sc[t] = rc[t];
  __syncthreads();
  for (int o = 1; o < 64; o <<= 1) {
    int v = (t >= o) ? sc[t - o] : 0;
    __syncthreads();
    sc[t] += v;
    __syncthreads();
  }
  int excl = sc[t] - rc[t];
  segoffs[b * 64 + t] = lo + excl;
  rcur[t] = excl;
  if (b == NB - 1 && t == 0) segoffs[NB * 64] = E;
  __syncthreads();
  for (int i = t; i < n; i += 64) {
    int v = pin[lo + i];
    int p = atomicAdd(&rcur[v >> 20], 1);
    srcl[lo + p] = v & 0xFFFFF;
  }
}

// ---------------- weight prep: fp32 [9][128][DOUT] -> bf16 transposed [9][DOUT][128] ----------------

__global__ void wprep_kernel(const float* __restrict__ Wrel, const float* __restrict__ Wroot,
                             unsigned short* __restrict__ wt, int DOUT) {
  int total = 9 * 128 * DOUT;
  int stride = gridDim.x * blockDim.x;
  for (int i = blockIdx.x * blockDim.x + threadIdx.x; i < total; i += stride) {
    int k = i & 127;
    int oo = i >> 7;           // rr*DOUT + o
    int o = oo % DOUT;
    int rr = oo / DOUT;
    float v = (rr < 8) ? Wrel[((size_t)rr * 128 + k) * DOUT + o]
                       : Wroot[(size_t)k * DOUT + o];
    wt[i] = f2b(v);
  }
}

// ---------------- aggregation: Y[rg][d] = sum_{e in seg(r0+rg,d)} x[src_e] ------
// 1 wave per dst row, 4 relations; zero LDS, no barriers, 4-batched loads.

__launch_bounds__(256)
__global__ void agg_kernel(const unsigned* __restrict__ x32,   // [N][64] dwords
                           const int* __restrict__ segoffs,    // [NB*64+1]
                           const int* __restrict__ srcl,       // [E] src only
                           unsigned* __restrict__ Y,           // [4][NTr][64] dwords
                           int r0, int NT, int NTr, int N) {
  int lane = threadIdx.x & 63;
  int d = (blockIdx.x * blockDim.x + threadIdx.x) >> 6;
  if (d >= N) return;
  int tile = d >> 6, row = d & 63;
#pragma unroll
  for (int rg = 0; rg < 4; ++rg) {
    int idx = ((r0 + rg) * NT + tile) * 64 + row;
    int lo = segoffs[idx], hi = segoffs[idx + 1];
    float s0 = 0.f, s1 = 0.f;
    int i = lo;
    for (; i + 4 <= hi; i += 4) {
      int sA = srcl[i], sB = srcl[i + 1], sC = srcl[i + 2], sD = srcl[i + 3];
      unsigned vA = x32[(size_t)sA * 64 + lane];
      unsigned vB = x32[(size_t)sB * 64 + lane];
      unsigned vC = x32[(size_t)sC * 64 + lane];
      unsigned vD = x32[(size_t)sD * 64 + lane];
      s0 += b2f((unsigned short)(vA & 0xFFFFu)) + b2f((unsigned short)(vB & 0xFFFFu))
          + b2f((unsigned short)(vC & 0xFFFFu)) + b2f((unsigned short)(vD & 0xFFFFu));
      s1 += b2f((unsigned short)(vA >> 16)) + b2f((unsigned short)(vB >> 16))
          + b2f((unsigned short)(vC >> 16)) + b2f((unsigned short)(vD >> 16));
    }
    for (; i < hi; ++i) {
      unsigned v = x32[(size_t)srcl[i] * 64 + lane];
      s0 += b2f((unsigned short)(v & 0xFFFFu));
      s1 += b2f((unsigned short)(v >> 16));
    }
    Y[((size_t)rg * NTr + d) * 64 + lane] = (unsigned)f2b(s0) | ((unsigned)f2b(s1) << 16);
  }
}

// ---------------- big-K GEMM: acc = sum_t A_t @ W_t ; zero LDS, no barriers ----------------

struct KTiles { const unsigned short* a[5]; const unsigned short* w[5]; };

// EPI: 0 = +bias -> bf16 partial; 1 = +partial, relu -> bf16; 2 = +partial, log-softmax -> f32
template <int DOUT, int NK, int EPI>
__launch_bounds__(256)
__global__ void gemm_big(KTiles kt, const float* __restrict__ bias,
                         const unsigned short* __restrict__ partial,
                         unsigned short* __restrict__ out_b,
                         float* __restrict__ out_f, int N) {
  int tid = threadIdx.x, wid = tid >> 6, lane = tid & 63;
  int colb = lane & 15, kgrp = lane >> 4;
  int rowbase = blockIdx.x * 128 + wid * 32;

  f32x4 acc[2][DOUT / 16];
#pragma unroll
  for (int t = 0; t < 2; ++t)
#pragma unroll
    for (int nf = 0; nf < DOUT / 16; ++nf) {
      f32x4 z = {0.f, 0.f, 0.f, 0.f};
      acc[t][nf] = z;
    }

  int ra = rowbase + colb, rb = ra + 16;
  size_t oa = (size_t)(ra < N ? ra : 0) * 128;
  size_t ob = (size_t)(rb < N ? rb : 0) * 128;

#pragma unroll
  for (int t = 0; t < NK; ++t) {
    const unsigned short* A = kt.a[t];
    const unsigned short* W = kt.w[t];
#pragma unroll
    for (int kk = 0; kk < 4; ++kk) {
      int kbase = kk * 32 + kgrp * 8;
      bf16x8 a0 = *(const bf16x8*)(A + oa + kbase);
      bf16x8 a1 = *(const bf16x8*)(A + ob + kbase);
#pragma unroll
      for (int nf = 0; nf < DOUT / 16; ++nf) {
        bf16x8 b = *(const bf16x8*)(W + (size_t)(nf * 16 + colb) * 128 + kbase);
        acc[0][nf] = __builtin_amdgcn_mfma_f32_16x16x32_bf16(a0, b, acc[0][nf], 0, 0, 0);
        acc[1][nf] = __builtin_amdgcn_mfma_f32_16x16x32_bf16(a1, b, acc[1][nf], 0, 0, 0);
      }
    }
  }

  float bv[DOUT / 16];
  if (EPI == 0) {
#pragma unroll
    for (int nf = 0; nf < DOUT / 16; ++nf) bv[nf] = bias[nf * 16 + colb];
  }

#pragma unroll
  for (int t = 0; t < 2; ++t) {
#pragma unroll
    for (int i = 0; i < 4; ++i) {
      int row = rowbase + t * 16 + kgrp * 4 + i;
      if (row >= N) continue;
      if (EPI == 0) {
#pragma unroll
        for (int nf = 0; nf < DOUT / 16; ++nf)
          out_b[(size_t)row * DOUT + nf * 16 + colb] = f2b(acc[t][nf][i] + bv[nf]);
      } else if (EPI == 1) {
#pragma unroll
        for (int nf = 0; nf < DOUT / 16; ++nf) {
          int col = nf * 16 + colb;
          float v = acc[t][nf][i] + b2f(partial[(size_t)row * DOUT + col]);
          out_b[(size_t)row * DOUT + col] = f2b(fmaxf(v, 0.f));
        }
      } else {
        // DOUT==64 log-softmax: row's 64 cols live in this 16-lane group
        float v[4];
#pragma unroll
        for (int nf = 0; nf < 4; ++nf)
          v[nf] = acc[t][nf][i] + b2f(partial[(size_t)row * 64 + nf * 16 + colb]);
        float m = fmaxf(fmaxf(v[0], v[1]), fmaxf(v[2], v[3]));
#pragma unroll
        for (int s = 1; s < 16; s <<= 1) m = fmaxf(m, __shfl_xor(m, s));
        float sum = 0.f;
#pragma unroll
        for (int nf = 0; nf < 4; ++nf) sum += __expf(v[nf] - m);
#pragma unroll
        for (int s = 1; s < 16; s <<= 1) sum += __shfl_xor(sum, s);
        float lse = m + __logf(sum);
#pragma unroll
        for (int nf = 0; nf < 4; ++nf)
          out_f[(size_t)row * 64 + nf * 16 + colb] = v[nf] - lse;
      }
    }
  }
}

// ---------------- input cast ----------------

__global__ void cast_kernel(const float* __restrict__ in, unsigned short* __restrict__ out,
                            int n4) {
  int stride = gridDim.x * blockDim.x;
  for (int i = blockIdx.x * blockDim.x + threadIdx.x; i < n4; i += stride) {
    float4 v = ((const float4*)in)[i];
    ushort4 o;
    o.x = f2b(v.x); o.y = f2b(v.y); o.z = f2b(v.z); o.w = f2b(v.w);
    ((ushort4*)out)[i] = o;
  }
}

// ---------------- launch ----------------

extern "C" void kernel_launch(void* const* d_in, const int* in_sizes, int n_in,
                              void* d_out, int out_size, void* d_ws, size_t ws_size,
                              hipStream_t stream) {
  const float* x = (const float*)d_in[0];
  const int* eidx = (const int*)d_in[1];     // int32
  const int* et = (const int*)d_in[2];       // int32
  const float* Wrel1 = (const float*)d_in[3];
  const float* Wroot1 = (const float*)d_in[4];
  const float* b1 = (const float*)d_in[5];
  const float* Wrel2 = (const float*)d_in[6];
  const float* Wroot2 = (const float*)d_in[7];
  const float* b2 = (const float*)d_in[8];
  const float* Wrel3 = (const float*)d_in[9];
  const float* Wroot3 = (const float*)d_in[10];
  const float* b3 = (const float*)d_in[11];

  const int N = in_sizes[0] / 128;    // 100000
  const int E = in_sizes[2];          // 1600000
  const int NT = (N + 63) / 64;       // 1563 dst tiles
  const int NTr = NT * 64;            // padded row count
  const int NB = 8 * NT;              // 12504 buckets
  const int* esrc = eidx;
  const int* edst = eidx + E;

  char* p = (char*)d_ws;
  auto carve = [&](size_t bytes) {
    void* q = (void*)p;
    p += (bytes + 255) & ~(size_t)255;
    return q;
  };
  unsigned short* bufX0 = (unsigned short*)carve((size_t)NTr * 128 * 2);   // 25.6 MB
  unsigned short* bufX1 = (unsigned short*)carve((size_t)NTr * 128 * 2);   // 25.6 MB
  unsigned short* part = (unsigned short*)carve((size_t)NTr * 128 * 2);    // 25.6 MB
  unsigned short* wt1 = (unsigned short*)carve((size_t)9 * 128 * 128 * 2);
  unsigned short* wt2 = (unsigned short*)carve((size_t)9 * 128 * 128 * 2);
  unsigned short* wt3 = (unsigned short*)carve((size_t)9 * 64 * 128 * 2);
  int* packed = (int*)carve((size_t)E * 4);                                // 6.4 MB
  int* srcl = (int*)carve((size_t)E * 4);                                  // 6.4 MB
  int* cnt = (int*)carve((size_t)NB * 4);
  int* offs = (int*)carve((size_t)(NB + 1) * 4);
  int* cursor = (int*)carve((size_t)NB * 4);
  int* segoffs = (int*)carve(((size_t)NB * 64 + 1) * 4);                   // 3.2 MB
  const int nbs = (NB + 255) / 256;
  int* bsum = (int*)carve((size_t)nbs * 4);
  unsigned short* Y = (unsigned short*)carve((size_t)4 * NTr * 128 * 2);   // 102.4 MB

  // ---- bucket sort + per-bucket row sort (once; reused by all 3 layers) ----
  k_zero2<<<64, 256, 0, stream>>>(cnt, NB);
  k_hist2<<<2048, 256, 0, stream>>>(et, edst, cnt, NT, E);
  k_scan1<<<nbs, 256, 0, stream>>>(cnt, offs, bsum, NB);
  k_scan2<<<1, 256, 0, stream>>>(bsum, nbs);
  k_scan3<<<nbs, 256, 0, stream>>>(offs, bsum, cursor, NB, E);
  k_fill2<<<2048, 256, 0, stream>>>(et, esrc, edst, cursor, packed, NT, E);
  k_seg<<<NB, 64, 0, stream>>>(offs, packed, srcl, segoffs, NB, E);

  // ---- weight prep + input cast ----
  wprep_kernel<<<576, 256, 0, stream>>>(Wrel1, Wroot1, wt1, 128);
  wprep_kernel<<<576, 256, 0, stream>>>(Wrel2, Wroot2, wt2, 128);
  wprep_kernel<<<288, 256, 0, stream>>>(Wrel3, Wroot3, wt3, 64);
  cast_kernel<<<2048, 256, 0, stream>>>(x, bufX0, N * 128 / 4);

  const int gblk = (NTr + 127) / 128;
  const int ablk = (N * 64 + 255) / 256;    // 1 wave per dst row
  const size_t Ystep = (size_t)NTr * 128;

  auto layer128 = [&](const unsigned short* xin, const unsigned short* wt,
                      const float* bias, unsigned short* xout) {
    agg_kernel<<<ablk, 256, 0, stream>>>((const unsigned*)xin, segoffs, srcl, (unsigned*)Y, 0, NT, NTr, N);
    KTiles kt1;
    kt1.a[0] = xin;            kt1.w[0] = wt + (size_t)8 * 128 * 128;
    for (int j = 0; j < 4; ++j) { kt1.a[j + 1] = Y + Ystep * j; kt1.w[j + 1] = wt + (size_t)j * 128 * 128; }
    gemm_big<128, 5, 0><<<gblk, 256, 0, stream>>>(kt1, bias, (const unsigned short*)nullptr, part, (float*)nullptr, N);
    agg_kernel<<<ablk, 256, 0, stream>>>((const unsigned*)xin, segoffs, srcl, (unsigned*)Y, 4, NT, NTr, N);
    KTiles kt2;
    for (int j = 0; j < 4; ++j) { kt2.a[j] = Y + Ystep * j; kt2.w[j] = wt + (size_t)(4 + j) * 128 * 128; }
    kt2.a[4] = kt2.a[0]; kt2.w[4] = kt2.w[0];
    gemm_big<128, 4, 1><<<gblk, 256, 0, stream>>>(kt2, (const float*)nullptr, part, xout, (float*)nullptr, N);
  };

  layer128(bufX0, wt1, b1, bufX1);
  layer128(bufX1, wt2, b2, bufX0);

  // ---- layer 3 (128 -> 64, fused log-softmax) ----
  agg_kernel<<<ablk, 256, 0, stream>>>((const unsigned*)bufX0, segoffs, srcl, (unsigned*)Y, 0, NT, NTr, N);
  KTiles kt1;
  kt1.a[0] = bufX0;           kt1.w[0] = wt3 + (size_t)8 * 64 * 128;
  for (int j = 0; j < 4; ++j) { kt1.a[j + 1] = Y + Ystep * j; kt1.w[j + 1] = wt3 + (size_t)j * 64 * 128; }
  gemm_big<64, 5, 0><<<gblk, 256, 0, stream>>>(kt1, b3, (const unsigned short*)nullptr, part, (float*)nullptr, N);
  agg_kernel<<<ablk, 256, 0, stream>>>((const unsigned*)bufX0, segoffs, srcl, (unsigned*)Y, 4, NT, NTr, N);
  KTiles kt2;
  for (int j = 0; j < 4; ++j) { kt2.a[j] = Y + Ystep * j; kt2.w[j] = wt3 + (size_t)(4 + j) * 64 * 128; }
  kt2.a[4] = kt2.a[0]; kt2.w[4] = kt2.w[0];
  gemm_big<64, 4, 2><<<gblk, 256, 0, stream>>>(kt2, (const float*)nullptr, part, (unsigned short*)nullptr, (float*)d_out, N);
}

// Round 8
// 1195.554 us; speedup vs baseline: 3.2676x; 1.0215x over previous
//
#include <hip/hip_runtime.h>

// RGCN 3-layer forward, MI355X — aggregate-then-transform v3.
// Identity: sum_e x[src_e] @ W_r == (sum_e x[src_e]) @ W_r.
// Round-7 lessons: (a) zero-LDS big-K GEMM was latency-bound (23% occ, scattered
// 16B A-loads) -> replaced with m97-style LDS-staged GEMM: 64-row tiles,
// global_load_lds width-16 double-buffered, XOR-swizzled chunks (pre-swizzled
// global source, swizzled ds_read_b128) for conflict-free LDS reads.
// (b) agg segments avg 2 edges -> shallow chains; now all NRP relation sections
// prefetch their first-2 edges' loads upfront (static unroll, ~32 independent
// loads in flight), uniform-branch tails. Y is K-concat [NTr][NRP*128] bf16.
// NRP adaptive {8,4,2} by ws_size (8 = single pass/layer, no partial buffer).

#define DEVI __device__ __forceinline__

typedef __attribute__((ext_vector_type(8))) short bf16x8;
typedef __attribute__((ext_vector_type(4))) float f32x4;

DEVI unsigned short f2b(float f) {
  unsigned int u = __builtin_bit_cast(unsigned int, f);
  unsigned int r = (u + 0x7FFFu + ((u >> 16) & 1u)) >> 16;
  return (unsigned short)r;
}
DEVI float b2f(unsigned short h) {
  unsigned int u = ((unsigned int)h) << 16;
  return __builtin_bit_cast(float, u);
}
DEVI float lo16f(unsigned v) { return __builtin_bit_cast(float, v << 16); }
DEVI float hi16f(unsigned v) { return __builtin_bit_cast(float, v & 0xFFFF0000u); }
DEVI int imin(int a, int b) { return a < b ? a : b; }

// ---------------- bucket sort by key = rel*NT + (dst>>6) ----------------

__global__ void k_zero2(int* __restrict__ cnt, int n) {
  int stride = gridDim.x * blockDim.x;
  for (int i = blockIdx.x * blockDim.x + threadIdx.x; i < n; i += stride) cnt[i] = 0;
}

__global__ void k_hist2(const int* __restrict__ et, const int* __restrict__ edst,
                        int* __restrict__ cnt, int NT, int E) {
  int stride = gridDim.x * blockDim.x;
  for (int i = blockIdx.x * blockDim.x + threadIdx.x; i < E; i += stride)
    atomicAdd(&cnt[(et[i] & 7) * NT + (edst[i] >> 6)], 1);
}

__global__ void k_scan1(const int* __restrict__ cnt, int* __restrict__ offs,
                        int* __restrict__ bsum, int KT) {
  __shared__ int l[256];
  int g = blockIdx.x * 256 + threadIdx.x;
  int v = (g < KT) ? cnt[g] : 0;
  l[threadIdx.x] = v;
  __syncthreads();
  for (int o = 1; o < 256; o <<= 1) {
    int t = (threadIdx.x >= o) ? l[threadIdx.x - o] : 0;
    __syncthreads();
    l[threadIdx.x] += t;
    __syncthreads();
  }
  if (g < KT) offs[g] = l[threadIdx.x] - v;
  if (threadIdx.x == 255) bsum[blockIdx.x] = l[255];
}

__global__ void k_scan2(int* __restrict__ bsum, int nb) {
  __shared__ int l[256];
  __shared__ int carry;
  if (threadIdx.x == 0) carry = 0;
  __syncthreads();
  for (int base = 0; base < nb; base += 256) {
    int g = base + threadIdx.x;
    int v = (g < nb) ? bsum[g] : 0;
    l[threadIdx.x] = v;
    __syncthreads();
    for (int o = 1; o < 256; o <<= 1) {
      int t = (threadIdx.x >= o) ? l[threadIdx.x - o] : 0;
      __syncthreads();
      l[threadIdx.x] += t;
      __syncthreads();
    }
    if (g < nb) bsum[g] = l[threadIdx.x] - v + carry;
    __syncthreads();
    if (threadIdx.x == 0) carry += l[255];
    __syncthreads();
  }
}

__global__ void k_scan3(int* __restrict__ offs, const int* __restrict__ bsum,
                        int* __restrict__ cursor, int KT, int E) {
  int g = blockIdx.x * 256 + threadIdx.x;
  if (g < KT) {
    int v = offs[g] + bsum[blockIdx.x];
    offs[g] = v;
    cursor[g] = v;
  }
  if (g == 0) offs[KT] = E;
}

__global__ void k_fill2(const int* __restrict__ et, const int* __restrict__ esrc,
                        const int* __restrict__ edst, int* __restrict__ cursor,
                        int* __restrict__ packed, int NT, int E) {
  int stride = gridDim.x * blockDim.x;
  for (int i = blockIdx.x * blockDim.x + threadIdx.x; i < E; i += stride) {
    int d = edst[i];
    int key = (et[i] & 7) * NT + (d >> 6);
    int pos = atomicAdd(&cursor[key], 1);
    packed[pos] = ((d & 63) << 20) | esrc[i];
  }
}

// per-bucket counting sort by row; outputs srcl grouped by row, plus rel-minor
// lo9/len9: index (tile*64+row)*8 + rel.
__global__ void k_seg(const int* __restrict__ boffs, const int* __restrict__ pin,
                      int* __restrict__ srcl, int* __restrict__ lo9,
                      int* __restrict__ len9, int NT) {
  __shared__ int rc[64], sc[64], rcur[64];
  int b = blockIdx.x;
  int r = b / NT, tile = b - r * NT;
  int lo = boffs[b], hi = boffs[b + 1], n = hi - lo;
  int t = threadIdx.x;
  rc[t] = 0;
  __syncthreads();
  for (int i = t; i < n; i += 64) atomicAdd(&rc[pin[lo + i] >> 20], 1);
  __syncthreads();
  sc[t] = rc[t];
  __syncthreads();
  for (int o = 1; o < 64; o <<= 1) {
    int v = (t >= o) ? sc[t - o] : 0;
    __syncthreads();
    sc[t] += v;
    __syncthreads();
  }
  int excl = sc[t] - rc[t];
  lo9[(tile * 64 + t) * 8 + r] = lo + excl;
  len9[(tile * 64 + t) * 8 + r] = rc[t];
  rcur[t] = excl;
  __syncthreads();
  for (int i = t; i < n; i += 64) {
    int v = pin[lo + i];
    int p = atomicAdd(&rcur[v >> 20], 1);
    srcl[lo + p] = v & 0xFFFFF;
  }
}

// ---------------- weight prep: fp32 [9][128][DOUT] -> bf16 [9][DOUT][128] ----------------

__global__ void wprep_kernel(const float* __restrict__ Wrel, const float* __restrict__ Wroot,
                             unsigned short* __restrict__ wt, int DOUT) {
  int total = 9 * 128 * DOUT;
  int stride = gridDim.x * blockDim.x;
  for (int i = blockIdx.x * blockDim.x + threadIdx.x; i < total; i += stride) {
    int k = i & 127;
    int oo = i >> 7;
    int o = oo % DOUT;
    int rr = oo / DOUT;
    float v = (rr < 8) ? Wrel[((size_t)rr * 128 + k) * DOUT + o]
                       : Wroot[(size_t)k * DOUT + o];
    wt[i] = f2b(v);
  }
}

// ---------------- aggregation: Y slice j = sum over seg(r0+j, d) of x[src] ----
// 1 wave per dst row; NRP relation sections statically unrolled; first-2 edges
// of every section prefetched upfront (independent loads), uniform tails.

template <int NRP>
__launch_bounds__(256)
__global__ void agg_kernel(const unsigned* __restrict__ x32,   // [NTr][64] dwords
                           const int* __restrict__ lo9, const int* __restrict__ len9,
                           const int* __restrict__ srcl,
                           unsigned* __restrict__ Ydw,         // [NTr][NRP*64] dwords
                           int r0, int N, int E) {
  int lane = threadIdx.x & 63;
  int d = (blockIdx.x * blockDim.x + threadIdx.x) >> 6;
  if (d >= N) return;
  int base = d * 8 + r0;

  int lo[NRP], ln[NRP];
#pragma unroll
  for (int r = 0; r < NRP; ++r) { lo[r] = lo9[base + r]; ln[r] = len9[base + r]; }

  int s0[NRP], s1[NRP];
#pragma unroll
  for (int r = 0; r < NRP; ++r) {
    s0[r] = srcl[imin(lo[r], E - 1)];
    s1[r] = srcl[imin(lo[r] + 1, E - 1)];
  }
  unsigned v0[NRP], v1[NRP];
#pragma unroll
  for (int r = 0; r < NRP; ++r) {
    v0[r] = x32[(size_t)s0[r] * 64 + lane];
    v1[r] = x32[(size_t)s1[r] * 64 + lane];
  }

#pragma unroll
  for (int r = 0; r < NRP; ++r) {
    float a0 = 0.f, a1 = 0.f;
    if (ln[r] > 0) { a0 += lo16f(v0[r]); a1 += hi16f(v0[r]); }
    if (ln[r] > 1) { a0 += lo16f(v1[r]); a1 += hi16f(v1[r]); }
    if (ln[r] > 2) {
      int i = lo[r] + 2, e = lo[r] + ln[r];
      for (; i + 2 <= e; i += 2) {
        int sA = srcl[i], sB = srcl[i + 1];
        unsigned vA = x32[(size_t)sA * 64 + lane];
        unsigned vB = x32[(size_t)sB * 64 + lane];
        a0 += lo16f(vA) + lo16f(vB);
        a1 += hi16f(vA) + hi16f(vB);
      }
      if (i < e) {
        unsigned vA = x32[(size_t)srcl[i] * 64 + lane];
        a0 += lo16f(vA);
        a1 += hi16f(vA);
      }
    }
    Ydw[(size_t)d * (NRP * 64) + r * 64 + lane] =
        (unsigned)f2b(a0) | ((unsigned)f2b(a1) << 16);
  }
}

// ---------------- LDS-staged GEMM: acc = sum_t A_t @ W_t ----------------
// 64-row tile, 4 waves x 16 rows, A staged via global_load_lds (16B), double
// buffer, XOR chunk swizzle (pre-swizzled global source + swizzled ds_read).

struct SrcArr {
  const unsigned short* a[9];
  const unsigned short* w[9];
  int st[9];
};

// EPI: 0=bias->bf16; 1=partial+relu->bf16; 2=partial+lsm->f32;
//      3=bias+relu->bf16; 4=bias+lsm->f32; 5=partial->bf16
template <int DOUT, int NK, int EPI>
__launch_bounds__(256)
__global__ void gemm_lds(SrcArr S, const float* __restrict__ bias,
                         const unsigned short* __restrict__ part,
                         unsigned short* __restrict__ out_b,
                         float* __restrict__ out_f, int N) {
  __shared__ unsigned short Al[2][64 * 128];
  int tid = threadIdx.x, wid = tid >> 6, lane = tid & 63;
  int colb = lane & 15, kgrp = lane >> 4;
  int tilebase = blockIdx.x * 64;

  auto stage = [&](int t, int buf) {
    const unsigned short* sa = S.a[t] + (size_t)tilebase * S.st[t];
    int st = S.st[t];
#pragma unroll
    for (int q = 0; q < 4; ++q) {
      int c = q * 256 + tid;
      int row = c >> 4, kcl = c & 15;
      int kcg = kcl ^ (row & 7);
      const unsigned short* gp = sa + (size_t)row * st + kcg * 8;
      unsigned short* lp = &Al[buf][(q * 256 + (tid & ~63)) * 8];
      __builtin_amdgcn_global_load_lds(
          (__attribute__((address_space(1))) void*)gp,
          (__attribute__((address_space(3))) void*)lp, 16, 0, 0);
    }
  };

  f32x4 acc[DOUT / 16];
#pragma unroll
  for (int nf = 0; nf < DOUT / 16; ++nf) {
    f32x4 z = {0.f, 0.f, 0.f, 0.f};
    acc[nf] = z;
  }

  stage(0, 0);
#pragma unroll
  for (int t = 0; t < NK; ++t) {
    __syncthreads();               // drains vmcnt -> stage(t) complete
    if (t + 1 < NK) stage(t + 1, (t + 1) & 1);
    const unsigned short* W = S.w[t];
    const unsigned short* Ab = Al[t & 1];
    int arow = wid * 16 + colb;
#pragma unroll
    for (int kk = 0; kk < 4; ++kk) {
      int kc = kk * 4 + kgrp;
      bf16x8 a = *(const bf16x8*)(Ab + (size_t)(arow * 16 + (kc ^ (arow & 7))) * 8);
#pragma unroll
      for (int nf = 0; nf < DOUT / 16; ++nf) {
        bf16x8 b = *(const bf16x8*)(W + (size_t)(nf * 16 + colb) * 128 + kc * 8);
        acc[nf] = __builtin_amdgcn_mfma_f32_16x16x32_bf16(a, b, acc[nf], 0, 0, 0);
      }
    }
  }

  // ---- epilogue ----
  float bv[DOUT / 16];
  if (EPI == 0 || EPI == 3 || EPI == 4) {
#pragma unroll
    for (int nf = 0; nf < DOUT / 16; ++nf) bv[nf] = bias[nf * 16 + colb];
  }

#pragma unroll
  for (int i = 0; i < 4; ++i) {
    int row = tilebase + wid * 16 + kgrp * 4 + i;
    bool ok = row < N;
    int rc = ok ? row : 0;
    float v[DOUT / 16];
#pragma unroll
    for (int nf = 0; nf < DOUT / 16; ++nf) {
      v[nf] = acc[nf][i];
      if (EPI == 0 || EPI == 3 || EPI == 4) v[nf] += bv[nf];
      if (EPI == 1 || EPI == 2 || EPI == 5)
        v[nf] += b2f(part[(size_t)rc * DOUT + nf * 16 + colb]);
    }
    if (EPI == 2 || EPI == 4) {
      // DOUT==64 log-softmax over the 16-lane group
      float m = v[0];
#pragma unroll
      for (int nf = 1; nf < DOUT / 16; ++nf) m = fmaxf(m, v[nf]);
#pragma unroll
      for (int s = 1; s < 16; s <<= 1) m = fmaxf(m, __shfl_xor(m, s));
      float sum = 0.f;
#pragma unroll
      for (int nf = 0; nf < DOUT / 16; ++nf) sum += __expf(v[nf] - m);
#pragma unroll
      for (int s = 1; s < 16; s <<= 1) sum += __shfl_xor(sum, s);
      float lse = m + __logf(sum);
      if (ok) {
#pragma unroll
        for (int nf = 0; nf < DOUT / 16; ++nf)
          out_f[(size_t)row * DOUT + nf * 16 + colb] = v[nf] - lse;
      }
    } else {
      if (ok) {
#pragma unroll
        for (int nf = 0; nf < DOUT / 16; ++nf) {
          float o = v[nf];
          if (EPI == 1 || EPI == 3) o = fmaxf(o, 0.f);
          out_b[(size_t)row * DOUT + nf * 16 + colb] = f2b(o);
        }
      }
    }
  }
}

template <int DOUT>
static void run_gemm(int NK, int EPI, const SrcArr& S, const float* bias,
                     const unsigned short* part, unsigned short* ob, float* of,
                     int N, int NT, hipStream_t st) {
#define GCALL(nk, epi)                                                        \
  if (NK == nk && EPI == epi) {                                               \
    gemm_lds<DOUT, nk, epi><<<NT, 256, 0, st>>>(S, bias, part, ob, of, N);    \
    return;                                                                   \
  }
  GCALL(9, 3) GCALL(9, 4)
  GCALL(5, 0) GCALL(4, 1) GCALL(4, 2)
  GCALL(3, 0) GCALL(2, 5) GCALL(2, 1) GCALL(2, 2)
#undef GCALL
}

// ---------------- input cast ----------------

__global__ void cast_kernel(const float* __restrict__ in, unsigned short* __restrict__ out,
                            int n4) {
  int stride = gridDim.x * blockDim.x;
  for (int i = blockIdx.x * blockDim.x + threadIdx.x; i < n4; i += stride) {
    float4 v = ((const float4*)in)[i];
    ushort4 o;
    o.x = f2b(v.x); o.y = f2b(v.y); o.z = f2b(v.z); o.w = f2b(v.w);
    ((ushort4*)out)[i] = o;
  }
}

// ---------------- launch ----------------

extern "C" void kernel_launch(void* const* d_in, const int* in_sizes, int n_in,
                              void* d_out, int out_size, void* d_ws, size_t ws_size,
                              hipStream_t stream) {
  const float* x = (const float*)d_in[0];
  const int* eidx = (const int*)d_in[1];
  const int* et = (const int*)d_in[2];
  const float* Wrel1 = (const float*)d_in[3];
  const float* Wroot1 = (const float*)d_in[4];
  const float* b1 = (const float*)d_in[5];
  const float* Wrel2 = (const float*)d_in[6];
  const float* Wroot2 = (const float*)d_in[7];
  const float* b2 = (const float*)d_in[8];
  const float* Wrel3 = (const float*)d_in[9];
  const float* Wroot3 = (const float*)d_in[10];
  const float* b3 = (const float*)d_in[11];

  const int N = in_sizes[0] / 128;    // 100000
  const int E = in_sizes[2];          // 1600000
  const int NT = (N + 63) / 64;       // 1563
  const int NTr = NT * 64;            // 100032
  const int NB = 8 * NT;              // 12504
  const int* esrc = eidx;
  const int* edst = eidx + E;

  const size_t XB = (size_t)NTr * 128 * 2;   // 25.6 MB

  // fixed carve budget
  size_t fixedB = 2 * XB + 2 * ((size_t)9 * 128 * 128 * 2) + (size_t)9 * 64 * 128 * 2 +
                  2 * ((size_t)E * 4) + 2 * ((size_t)NB * 64 * 4) +
                  3 * ((size_t)NB * 4) + 4096 + 16 * 256;
  int NRP = 8;
  if (fixedB + 8 * XB > ws_size) NRP = 4;
  if (NRP == 4 && fixedB + 4 * XB + XB > ws_size) NRP = 2;

  char* p = (char*)d_ws;
  auto carve = [&](size_t bytes) {
    void* q = (void*)p;
    p += (bytes + 255) & ~(size_t)255;
    return q;
  };
  unsigned short* bufX0 = (unsigned short*)carve(XB);
  unsigned short* bufX1 = (unsigned short*)carve(XB);
  unsigned short* wt1 = (unsigned short*)carve((size_t)9 * 128 * 128 * 2);
  unsigned short* wt2 = (unsigned short*)carve((size_t)9 * 128 * 128 * 2);
  unsigned short* wt3 = (unsigned short*)carve((size_t)9 * 64 * 128 * 2);
  int* packed = (int*)carve((size_t)E * 4);
  int* srcl = (int*)carve((size_t)E * 4);
  int* lo9 = (int*)carve((size_t)NB * 64 * 4);
  int* len9 = (int*)carve((size_t)NB * 64 * 4);
  int* cnt = (int*)carve((size_t)NB * 4);
  int* offs = (int*)carve((size_t)(NB + 1) * 4);
  int* cursor = (int*)carve((size_t)NB * 4);
  const int nbs = (NB + 255) / 256;
  int* bsum = (int*)carve((size_t)nbs * 4);
  unsigned short* part = (unsigned short*)((NRP < 8) ? carve(XB) : nullptr);
  unsigned short* Y = (unsigned short*)carve((size_t)NRP * XB);

  // ---- sort: (rel,tile) buckets, then per-bucket row sort (once) ----
  k_zero2<<<64, 256, 0, stream>>>(cnt, NB);
  k_hist2<<<2048, 256, 0, stream>>>(et, edst, cnt, NT, E);
  k_scan1<<<nbs, 256, 0, stream>>>(cnt, offs, bsum, NB);
  k_scan2<<<1, 256, 0, stream>>>(bsum, nbs);
  k_scan3<<<nbs, 256, 0, stream>>>(offs, bsum, cursor, NB, E);
  k_fill2<<<2048, 256, 0, stream>>>(et, esrc, edst, cursor, packed, NT, E);
  k_seg<<<NB, 64, 0, stream>>>(offs, packed, srcl, lo9, len9, NT);

  // ---- weight prep + input cast ----
  wprep_kernel<<<576, 256, 0, stream>>>(Wrel1, Wroot1, wt1, 128);
  wprep_kernel<<<576, 256, 0, stream>>>(Wrel2, Wroot2, wt2, 128);
  wprep_kernel<<<288, 256, 0, stream>>>(Wrel3, Wroot3, wt3, 64);
  cast_kernel<<<2048, 256, 0, stream>>>(x, bufX0, N * 128 / 4);

  const int ablk = (N * 64 + 255) / 256;
  const int passes = 8 / NRP;

  auto layer = [&](const unsigned short* xin, const unsigned short* wt,
                   const float* bias, int DOUT, unsigned short* xout, float* fout) {
    for (int pidx = 0; pidx < passes; ++pidx) {
      int r0 = pidx * NRP;
      if (NRP == 8)
        agg_kernel<8><<<ablk, 256, 0, stream>>>((const unsigned*)xin, lo9, len9, srcl, (unsigned*)Y, r0, N, E);
      else if (NRP == 4)
        agg_kernel<4><<<ablk, 256, 0, stream>>>((const unsigned*)xin, lo9, len9, srcl, (unsigned*)Y, r0, N, E);
      else
        agg_kernel<2><<<ablk, 256, 0, stream>>>((const unsigned*)xin, lo9, len9, srcl, (unsigned*)Y, r0, N, E);

      SrcArr S;
      int idx = 0;
      if (pidx == 0) {
        S.a[0] = xin; S.w[0] = wt + (size_t)8 * DOUT * 128; S.st[0] = 128;
        idx = 1;
      }
      for (int j = 0; j < NRP; ++j) {
        S.a[idx] = Y + j * 128;
        S.w[idx] = wt + (size_t)(r0 + j) * DOUT * 128;
        S.st[idx] = NRP * 128;
        ++idx;
      }
      int NK = idx;
      int epi;
      bool lastp = (pidx == passes - 1);
      if (pidx == 0 && lastp) epi = (DOUT == 64) ? 4 : 3;
      else if (pidx == 0) epi = 0;
      else if (!lastp) epi = 5;
      else epi = (DOUT == 64) ? 2 : 1;

      unsigned short* ob = lastp ? xout : part;
      if (pidx == 0 && !lastp) ob = part;
      if (DOUT == 128)
        run_gemm<128>(NK, epi, S, bias, part, ob, fout, N, NT, stream);
      else
        run_gemm<64>(NK, epi, S, bias, part, ob, fout, N, NT, stream);
    }
  };

  layer(bufX0, wt1, b1, 128, bufX1, nullptr);
  layer(bufX1, wt2, b2, 128, bufX0, nullptr);
  layer(bufX0, wt3, b3, 64, nullptr, (float*)d_out);
}

// Round 9
// 834.327 us; speedup vs baseline: 4.6823x; 1.4330x over previous
//
#include <hip/hip_runtime.h>

// RGCN 3-layer forward, MI355X — aggregate-then-transform v4.
// Identity: sum_e x[src_e] @ W_r == (sum_e x[src_e]) @ W_r.
// Round-8 lesson: ALL prior GEMMs plateaued at ~120 TF because each MFMA pulled a
// fresh 1KB B-fragment from L2 (reuse=1); 56 B/cyc/CU L2 share caps MfmaUtil ~5%.
// v4: waves split COLUMNS (each wave: all 64 rows x DOUT/4 cols, acc[4][NF]) so
// each B-load feeds 4 MFMAs and per-block B traffic = one 32KB tile -> 256B/MFMA.
// A stays LDS-staged (global_load_lds width-16, double-buffered, XOR swizzle).
// DOUT=64 log-softmax epilogue reduces whole rows via LDS round-trip.

#define DEVI __device__ __forceinline__

typedef __attribute__((ext_vector_type(8))) short bf16x8;
typedef __attribute__((ext_vector_type(4))) float f32x4;

DEVI unsigned short f2b(float f) {
  unsigned int u = __builtin_bit_cast(unsigned int, f);
  unsigned int r = (u + 0x7FFFu + ((u >> 16) & 1u)) >> 16;
  return (unsigned short)r;
}
DEVI float b2f(unsigned short h) {
  unsigned int u = ((unsigned int)h) << 16;
  return __builtin_bit_cast(float, u);
}
DEVI float lo16f(unsigned v) { return __builtin_bit_cast(float, v << 16); }
DEVI float hi16f(unsigned v) { return __builtin_bit_cast(float, v & 0xFFFF0000u); }
DEVI int imin(int a, int b) { return a < b ? a : b; }

// ---------------- bucket sort by key = rel*NT + (dst>>6) ----------------

__global__ void k_zero2(int* __restrict__ cnt, int n) {
  int stride = gridDim.x * blockDim.x;
  for (int i = blockIdx.x * blockDim.x + threadIdx.x; i < n; i += stride) cnt[i] = 0;
}

__global__ void k_hist2(const int* __restrict__ et, const int* __restrict__ edst,
                        int* __restrict__ cnt, int NT, int E) {
  int stride = gridDim.x * blockDim.x;
  for (int i = blockIdx.x * blockDim.x + threadIdx.x; i < E; i += stride)
    atomicAdd(&cnt[(et[i] & 7) * NT + (edst[i] >> 6)], 1);
}

__global__ void k_scan1(const int* __restrict__ cnt, int* __restrict__ offs,
                        int* __restrict__ bsum, int KT) {
  __shared__ int l[256];
  int g = blockIdx.x * 256 + threadIdx.x;
  int v = (g < KT) ? cnt[g] : 0;
  l[threadIdx.x] = v;
  __syncthreads();
  for (int o = 1; o < 256; o <<= 1) {
    int t = (threadIdx.x >= o) ? l[threadIdx.x - o] : 0;
    __syncthreads();
    l[threadIdx.x] += t;
    __syncthreads();
  }
  if (g < KT) offs[g] = l[threadIdx.x] - v;
  if (threadIdx.x == 255) bsum[blockIdx.x] = l[255];
}

__global__ void k_scan2(int* __restrict__ bsum, int nb) {
  __shared__ int l[256];
  __shared__ int carry;
  if (threadIdx.x == 0) carry = 0;
  __syncthreads();
  for (int base = 0; base < nb; base += 256) {
    int g = base + threadIdx.x;
    int v = (g < nb) ? bsum[g] : 0;
    l[threadIdx.x] = v;
    __syncthreads();
    for (int o = 1; o < 256; o <<= 1) {
      int t = (threadIdx.x >= o) ? l[threadIdx.x - o] : 0;
      __syncthreads();
      l[threadIdx.x] += t;
      __syncthreads();
    }
    if (g < nb) bsum[g] = l[threadIdx.x] - v + carry;
    __syncthreads();
    if (threadIdx.x == 0) carry += l[255];
    __syncthreads();
  }
}

__global__ void k_scan3(int* __restrict__ offs, const int* __restrict__ bsum,
                        int* __restrict__ cursor, int KT, int E) {
  int g = blockIdx.x * 256 + threadIdx.x;
  if (g < KT) {
    int v = offs[g] + bsum[blockIdx.x];
    offs[g] = v;
    cursor[g] = v;
  }
  if (g == 0) offs[KT] = E;
}

__global__ void k_fill2(const int* __restrict__ et, const int* __restrict__ esrc,
                        const int* __restrict__ edst, int* __restrict__ cursor,
                        int* __restrict__ packed, int NT, int E) {
  int stride = gridDim.x * blockDim.x;
  for (int i = blockIdx.x * blockDim.x + threadIdx.x; i < E; i += stride) {
    int d = edst[i];
    int key = (et[i] & 7) * NT + (d >> 6);
    int pos = atomicAdd(&cursor[key], 1);
    packed[pos] = ((d & 63) << 20) | esrc[i];
  }
}

// per-bucket counting sort by row; outputs srcl grouped by row, plus rel-minor
// lo9/len9: index (tile*64+row)*8 + rel.
__global__ void k_seg(const int* __restrict__ boffs, const int* __restrict__ pin,
                      int* __restrict__ srcl, int* __restrict__ lo9,
                      int* __restrict__ len9, int NT) {
  __shared__ int rc[64], sc[64], rcur[64];
  int b = blockIdx.x;
  int r = b / NT, tile = b - r * NT;
  int lo = boffs[b], hi = boffs[b + 1], n = hi - lo;
  int t = threadIdx.x;
  rc[t] = 0;
  __syncthreads();
  for (int i = t; i < n; i += 64) atomicAdd(&rc[pin[lo + i] >> 20], 1);
  __syncthreads();
  sc[t] = rc[t];
  __syncthreads();
  for (int o = 1; o < 64; o <<= 1) {
    int v = (t >= o) ? sc[t - o] : 0;
    __syncthreads();
    sc[t] += v;
    __syncthreads();
  }
  int excl = sc[t] - rc[t];
  lo9[(tile * 64 + t) * 8 + r] = lo + excl;
  len9[(tile * 64 + t) * 8 + r] = rc[t];
  rcur[t] = excl;
  __syncthreads();
  for (int i = t; i < n; i += 64) {
    int v = pin[lo + i];
    int p = atomicAdd(&rcur[v >> 20], 1);
    srcl[lo + p] = v & 0xFFFFF;
  }
}

// ---------------- weight prep: fp32 [9][128][DOUT] -> bf16 [9][DOUT][128] ----------------

__global__ void wprep_kernel(const float* __restrict__ Wrel, const float* __restrict__ Wroot,
                             unsigned short* __restrict__ wt, int DOUT) {
  int total = 9 * 128 * DOUT;
  int stride = gridDim.x * blockDim.x;
  for (int i = blockIdx.x * blockDim.x + threadIdx.x; i < total; i += stride) {
    int k = i & 127;
    int oo = i >> 7;
    int o = oo % DOUT;
    int rr = oo / DOUT;
    float v = (rr < 8) ? Wrel[((size_t)rr * 128 + k) * DOUT + o]
                       : Wroot[(size_t)k * DOUT + o];
    wt[i] = f2b(v);
  }
}

// ---------------- aggregation: Y slice j = sum over seg(r0+j, d) of x[src] ----

template <int NRP>
__launch_bounds__(256)
__global__ void agg_kernel(const unsigned* __restrict__ x32,   // [NTr][64] dwords
                           const int* __restrict__ lo9, const int* __restrict__ len9,
                           const int* __restrict__ srcl,
                           unsigned* __restrict__ Ydw,         // [NTr][NRP*64] dwords
                           int r0, int N, int E) {
  int lane = threadIdx.x & 63;
  int d = (blockIdx.x * blockDim.x + threadIdx.x) >> 6;
  if (d >= N) return;
  int base = d * 8 + r0;

  int lo[NRP], ln[NRP];
#pragma unroll
  for (int r = 0; r < NRP; ++r) { lo[r] = lo9[base + r]; ln[r] = len9[base + r]; }

  int s0[NRP], s1[NRP];
#pragma unroll
  for (int r = 0; r < NRP; ++r) {
    s0[r] = srcl[imin(lo[r], E - 1)];
    s1[r] = srcl[imin(lo[r] + 1, E - 1)];
  }
  unsigned v0[NRP], v1[NRP];
#pragma unroll
  for (int r = 0; r < NRP; ++r) {
    v0[r] = x32[(size_t)s0[r] * 64 + lane];
    v1[r] = x32[(size_t)s1[r] * 64 + lane];
  }

#pragma unroll
  for (int r = 0; r < NRP; ++r) {
    float a0 = 0.f, a1 = 0.f;
    if (ln[r] > 0) { a0 += lo16f(v0[r]); a1 += hi16f(v0[r]); }
    if (ln[r] > 1) { a0 += lo16f(v1[r]); a1 += hi16f(v1[r]); }
    if (ln[r] > 2) {
      int i = lo[r] + 2, e = lo[r] + ln[r];
      for (; i + 2 <= e; i += 2) {
        int sA = srcl[i], sB = srcl[i + 1];
        unsigned vA = x32[(size_t)sA * 64 + lane];
        unsigned vB = x32[(size_t)sB * 64 + lane];
        a0 += lo16f(vA) + lo16f(vB);
        a1 += hi16f(vA) + hi16f(vB);
      }
      if (i < e) {
        unsigned vA = x32[(size_t)srcl[i] * 64 + lane];
        a0 += lo16f(vA);
        a1 += hi16f(vA);
      }
    }
    Ydw[(size_t)d * (NRP * 64) + r * 64 + lane] =
        (unsigned)f2b(a0) | ((unsigned)f2b(a1) << 16);
  }
}

// ---------------- LDS-staged GEMM, col-split waves: acc = sum_t A_t @ W_t -------
// 64-row tile; wave w owns ALL 64 rows x (DOUT/4) cols -> each B-load feeds 4
// MFMAs (row-blocks), per-block B traffic = one B-tile. A via global_load_lds
// (16B, dbuf, XOR chunk swizzle: pre-swizzled global source + swizzled ds_read).

struct SrcArr {
  const unsigned short* a[9];
  const unsigned short* w[9];
  int st[9];
};

// EPI: 0=bias->bf16; 1=partial+relu->bf16; 2=partial+lsm->f32;
//      3=bias+relu->bf16; 4=bias+lsm->f32; 5=partial->bf16
template <int DOUT, int NK, int EPI>
__launch_bounds__(256)
__global__ void gemm_lds(SrcArr S, const float* __restrict__ bias,
                         const unsigned short* __restrict__ part,
                         unsigned short* __restrict__ out_b,
                         float* __restrict__ out_f, int N) {
  __shared__ unsigned short Al[2][64 * 128];
  constexpr int NF = (DOUT == 128) ? 2 : 1;   // col-fragments per wave
  int tid = threadIdx.x, wid = tid >> 6, lane = tid & 63;
  int colb = lane & 15, kgrp = lane >> 4;
  int colw = wid * 16 * NF;                   // wave's column base
  int tilebase = blockIdx.x * 64;

  auto stage = [&](int t, int buf) {
    const unsigned short* sa = S.a[t] + (size_t)tilebase * S.st[t];
    int st = S.st[t];
#pragma unroll
    for (int q = 0; q < 4; ++q) {
      int c = q * 256 + tid;
      int row = c >> 4, kcl = c & 15;
      int kcg = kcl ^ (row & 7);
      const unsigned short* gp = sa + (size_t)row * st + kcg * 8;
      unsigned short* lp = &Al[buf][(q * 256 + (tid & ~63)) * 8];
      __builtin_amdgcn_global_load_lds(
          (__attribute__((address_space(1))) void*)gp,
          (__attribute__((address_space(3))) void*)lp, 16, 0, 0);
    }
  };

  f32x4 acc[4][NF];
#pragma unroll
  for (int rb = 0; rb < 4; ++rb)
#pragma unroll
    for (int nf = 0; nf < NF; ++nf) {
      f32x4 z = {0.f, 0.f, 0.f, 0.f};
      acc[rb][nf] = z;
    }

  stage(0, 0);
#pragma unroll
  for (int t = 0; t < NK; ++t) {
    __syncthreads();               // drains vmcnt -> stage(t) complete
    if (t + 1 < NK) stage(t + 1, (t + 1) & 1);
    const unsigned short* W = S.w[t];
    const unsigned short* Ab = Al[t & 1];
#pragma unroll
    for (int kk = 0; kk < 4; ++kk) {
      int kc = kk * 4 + kgrp;
      bf16x8 a[4];
#pragma unroll
      for (int rb = 0; rb < 4; ++rb) {
        int arow = rb * 16 + colb;
        a[rb] = *(const bf16x8*)(Ab + (size_t)(arow * 16 + (kc ^ (arow & 7))) * 8);
      }
#pragma unroll
      for (int nf = 0; nf < NF; ++nf) {
        bf16x8 b = *(const bf16x8*)(W + (size_t)(colw + nf * 16 + colb) * 128 + kc * 8);
#pragma unroll
        for (int rb = 0; rb < 4; ++rb)
          acc[rb][nf] = __builtin_amdgcn_mfma_f32_16x16x32_bf16(a[rb], b, acc[rb][nf], 0, 0, 0);
      }
    }
  }

  // ---- epilogue ----
  float bv[NF];
  if (EPI == 0 || EPI == 3 || EPI == 4) {
#pragma unroll
    for (int nf = 0; nf < NF; ++nf) bv[nf] = bias[colw + nf * 16 + colb];
  }

  if ((EPI == 2 || EPI == 4) && DOUT == 64) {
    // log-softmax: stage fp32 rows into LDS (reuse Al), reduce per row.
    float* Lf = (float*)Al;       // [64][68] padded
    __syncthreads();              // all MFMA ds_reads of Al done
#pragma unroll
    for (int rb = 0; rb < 4; ++rb)
#pragma unroll
      for (int i = 0; i < 4; ++i) {
        int row = rb * 16 + kgrp * 4 + i;
        int grow = tilebase + row;
        int rc = grow < N ? grow : 0;
        float v = acc[rb][0][i];
        if (EPI == 4) v += bv[0];
        else v += b2f(part[(size_t)rc * 64 + colw + colb]);
        Lf[row * 68 + colw + colb] = v;
      }
    __syncthreads();
#pragma unroll
    for (int it = 0; it < 4; ++it) {
      int row = wid * 16 + it * 4 + (lane >> 4);
      float v[4];
#pragma unroll
      for (int j = 0; j < 4; ++j) v[j] = Lf[row * 68 + colb + j * 16];
      float m = fmaxf(fmaxf(v[0], v[1]), fmaxf(v[2], v[3]));
#pragma unroll
      for (int s = 1; s < 16; s <<= 1) m = fmaxf(m, __shfl_xor(m, s));
      float sum = 0.f;
#pragma unroll
      for (int j = 0; j < 4; ++j) sum += __expf(v[j] - m);
#pragma unroll
      for (int s = 1; s < 16; s <<= 1) sum += __shfl_xor(sum, s);
      float lse = m + __logf(sum);
      int grow = tilebase + row;
      if (grow < N) {
#pragma unroll
        for (int j = 0; j < 4; ++j)
          out_f[(size_t)grow * 64 + colb + j * 16] = v[j] - lse;
      }
    }
  } else {
#pragma unroll
    for (int rb = 0; rb < 4; ++rb)
#pragma unroll
      for (int i = 0; i < 4; ++i) {
        int row = tilebase + rb * 16 + kgrp * 4 + i;
        bool ok = row < N;
        int rc = ok ? row : 0;
#pragma unroll
        for (int nf = 0; nf < NF; ++nf) {
          int col = colw + nf * 16 + colb;
          float v = acc[rb][nf][i];
          if (EPI == 0 || EPI == 3) v += bv[nf];
          if (EPI == 1 || EPI == 5) v += b2f(part[(size_t)rc * DOUT + col]);
          if (EPI == 1 || EPI == 3) v = fmaxf(v, 0.f);
          if (ok) out_b[(size_t)row * DOUT + col] = f2b(v);
        }
      }
  }
}

template <int DOUT>
static void run_gemm(int NK, int EPI, const SrcArr& S, const float* bias,
                     const unsigned short* part, unsigned short* ob, float* of,
                     int N, int NT, hipStream_t st) {
#define GCALL(nk, epi)                                                        \
  if (NK == nk && EPI == epi) {                                               \
    gemm_lds<DOUT, nk, epi><<<NT, 256, 0, st>>>(S, bias, part, ob, of, N);    \
    return;                                                                   \
  }
  GCALL(9, 3) GCALL(9, 4)
  GCALL(5, 0) GCALL(4, 1) GCALL(4, 2)
  GCALL(3, 0) GCALL(2, 5) GCALL(2, 1) GCALL(2, 2)
#undef GCALL
}

// ---------------- input cast ----------------

__global__ void cast_kernel(const float* __restrict__ in, unsigned short* __restrict__ out,
                            int n4) {
  int stride = gridDim.x * blockDim.x;
  for (int i = blockIdx.x * blockDim.x + threadIdx.x; i < n4; i += stride) {
    float4 v = ((const float4*)in)[i];
    ushort4 o;
    o.x = f2b(v.x); o.y = f2b(v.y); o.z = f2b(v.z); o.w = f2b(v.w);
    ((ushort4*)out)[i] = o;
  }
}

// ---------------- launch ----------------

extern "C" void kernel_launch(void* const* d_in, const int* in_sizes, int n_in,
                              void* d_out, int out_size, void* d_ws, size_t ws_size,
                              hipStream_t stream) {
  const float* x = (const float*)d_in[0];
  const int* eidx = (const int*)d_in[1];
  const int* et = (const int*)d_in[2];
  const float* Wrel1 = (const float*)d_in[3];
  const float* Wroot1 = (const float*)d_in[4];
  const float* b1 = (const float*)d_in[5];
  const float* Wrel2 = (const float*)d_in[6];
  const float* Wroot2 = (const float*)d_in[7];
  const float* b2 = (const float*)d_in[8];
  const float* Wrel3 = (const float*)d_in[9];
  const float* Wroot3 = (const float*)d_in[10];
  const float* b3 = (const float*)d_in[11];

  const int N = in_sizes[0] / 128;    // 100000
  const int E = in_sizes[2];          // 1600000
  const int NT = (N + 63) / 64;       // 1563
  const int NTr = NT * 64;            // 100032
  const int NB = 8 * NT;              // 12504
  const int* esrc = eidx;
  const int* edst = eidx + E;

  const size_t XB = (size_t)NTr * 128 * 2;   // 25.6 MB

  size_t fixedB = 2 * XB + 2 * ((size_t)9 * 128 * 128 * 2) + (size_t)9 * 64 * 128 * 2 +
                  2 * ((size_t)E * 4) + 2 * ((size_t)NB * 64 * 4) +
                  3 * ((size_t)NB * 4) + 4096 + 16 * 256;
  int NRP = 8;
  if (fixedB + 8 * XB > ws_size) NRP = 4;
  if (NRP == 4 && fixedB + 4 * XB + XB > ws_size) NRP = 2;

  char* p = (char*)d_ws;
  auto carve = [&](size_t bytes) {
    void* q = (void*)p;
    p += (bytes + 255) & ~(size_t)255;
    return q;
  };
  unsigned short* bufX0 = (unsigned short*)carve(XB);
  unsigned short* bufX1 = (unsigned short*)carve(XB);
  unsigned short* wt1 = (unsigned short*)carve((size_t)9 * 128 * 128 * 2);
  unsigned short* wt2 = (unsigned short*)carve((size_t)9 * 128 * 128 * 2);
  unsigned short* wt3 = (unsigned short*)carve((size_t)9 * 64 * 128 * 2);
  int* packed = (int*)carve((size_t)E * 4);
  int* srcl = (int*)carve((size_t)E * 4);
  int* lo9 = (int*)carve((size_t)NB * 64 * 4);
  int* len9 = (int*)carve((size_t)NB * 64 * 4);
  int* cnt = (int*)carve((size_t)NB * 4);
  int* offs = (int*)carve((size_t)(NB + 1) * 4);
  int* cursor = (int*)carve((size_t)NB * 4);
  const int nbs = (NB + 255) / 256;
  int* bsum = (int*)carve((size_t)nbs * 4);
  unsigned short* part = (unsigned short*)((NRP < 8) ? carve(XB) : nullptr);
  unsigned short* Y = (unsigned short*)carve((size_t)NRP * XB);

  // ---- sort: (rel,tile) buckets, then per-bucket row sort (once) ----
  k_zero2<<<64, 256, 0, stream>>>(cnt, NB);
  k_hist2<<<2048, 256, 0, stream>>>(et, edst, cnt, NT, E);
  k_scan1<<<nbs, 256, 0, stream>>>(cnt, offs, bsum, NB);
  k_scan2<<<1, 256, 0, stream>>>(bsum, nbs);
  k_scan3<<<nbs, 256, 0, stream>>>(offs, bsum, cursor, NB, E);
  k_fill2<<<2048, 256, 0, stream>>>(et, esrc, edst, cursor, packed, NT, E);
  k_seg<<<NB, 64, 0, stream>>>(offs, packed, srcl, lo9, len9, NT);

  // ---- weight prep + input cast ----
  wprep_kernel<<<576, 256, 0, stream>>>(Wrel1, Wroot1, wt1, 128);
  wprep_kernel<<<576, 256, 0, stream>>>(Wrel2, Wroot2, wt2, 128);
  wprep_kernel<<<288, 256, 0, stream>>>(Wrel3, Wroot3, wt3, 64);
  cast_kernel<<<2048, 256, 0, stream>>>(x, bufX0, N * 128 / 4);

  const int ablk = (N * 64 + 255) / 256;
  const int passes = 8 / NRP;

  auto layer = [&](const unsigned short* xin, const unsigned short* wt,
                   const float* bias, int DOUT, unsigned short* xout, float* fout) {
    for (int pidx = 0; pidx < passes; ++pidx) {
      int r0 = pidx * NRP;
      if (NRP == 8)
        agg_kernel<8><<<ablk, 256, 0, stream>>>((const unsigned*)xin, lo9, len9, srcl, (unsigned*)Y, r0, N, E);
      else if (NRP == 4)
        agg_kernel<4><<<ablk, 256, 0, stream>>>((const unsigned*)xin, lo9, len9, srcl, (unsigned*)Y, r0, N, E);
      else
        agg_kernel<2><<<ablk, 256, 0, stream>>>((const unsigned*)xin, lo9, len9, srcl, (unsigned*)Y, r0, N, E);

      SrcArr S;
      int idx = 0;
      if (pidx == 0) {
        S.a[0] = xin; S.w[0] = wt + (size_t)8 * DOUT * 128; S.st[0] = 128;
        idx = 1;
      }
      for (int j = 0; j < NRP; ++j) {
        S.a[idx] = Y + j * 128;
        S.w[idx] = wt + (size_t)(r0 + j) * DOUT * 128;
        S.st[idx] = NRP * 128;
        ++idx;
      }
      int NK = idx;
      int epi;
      bool lastp = (pidx == passes - 1);
      if (pidx == 0 && lastp) epi = (DOUT == 64) ? 4 : 3;
      else if (pidx == 0) epi = 0;
      else if (!lastp) epi = 5;
      else epi = (DOUT == 64) ? 2 : 1;

      unsigned short* ob = lastp ? xout : part;
      if (pidx == 0 && !lastp) ob = part;
      if (DOUT == 128)
        run_gemm<128>(NK, epi, S, bias, part, ob, fout, N, NT, stream);
      else
        run_gemm<64>(NK, epi, S, bias, part, ob, fout, N, NT, stream);
    }
  };

  layer(bufX0, wt1, b1, 128, bufX1, nullptr);
  layer(bufX1, wt2, b2, 128, bufX0, nullptr);
  layer(bufX0, wt3, b3, 64, nullptr, (float*)d_out);
}

// Round 10
// 694.364 us; speedup vs baseline: 5.6261x; 1.2016x over previous
//
#include <hip/hip_runtime.h>

// RGCN 3-layer forward, MI355X — aggregate-then-transform v5.
// Identity: sum_e x[src_e] @ W_r == (sum_e x[src_e]) @ W_r.
// Round-9 lesson: the edge sort was the top cost — k_fill2's per-edge random 4B
// scatter writes through to HBM (93 MB WRITE per call). v5 sort: (1) coarse
// 104-bin (rel x 128-tile-group) histogram+scan; (2) k_cfill: per-block bulk
// reservation + private contiguous sub-segments per bin (writes merge in L2);
// (3) k_fine: one block per bin, in-LDS counting sort over 8192 (tile,row) keys
// -> srcl grouped by (rel,d) + rel-major lo9/len9, all writes block-localized.
// Replaces the old hist/scan x3/fill/seg pipeline.
// GEMM: v4 col-split waves (B-reuse 4x), A via global_load_lds dbuf + XOR swizzle.
// Agg: 1 wave per dst row, NRP rels statically prefetched.

#define DEVI __device__ __forceinline__

typedef __attribute__((ext_vector_type(8))) short bf16x8;
typedef __attribute__((ext_vector_type(4))) float f32x4;

DEVI unsigned short f2b(float f) {
  unsigned int u = __builtin_bit_cast(unsigned int, f);
  unsigned int r = (u + 0x7FFFu + ((u >> 16) & 1u)) >> 16;
  return (unsigned short)r;
}
DEVI float b2f(unsigned short h) {
  unsigned int u = ((unsigned int)h) << 16;
  return __builtin_bit_cast(float, u);
}
DEVI float lo16f(unsigned v) { return __builtin_bit_cast(float, v << 16); }
DEVI float hi16f(unsigned v) { return __builtin_bit_cast(float, v & 0xFFFF0000u); }
DEVI int imin(int a, int b) { return a < b ? a : b; }

// ---------------- sort v5: coarse bins = rel*NG + (tile>>7), NG=ceil(NT/128) ----

__global__ void k_zero2(int* __restrict__ cnt, int n) {
  int stride = gridDim.x * blockDim.x;
  for (int i = blockIdx.x * blockDim.x + threadIdx.x; i < n; i += stride) cnt[i] = 0;
}

__global__ void k_chist(const int* __restrict__ et, const int* __restrict__ edst,
                        int* __restrict__ gh, int NG, int E) {
  __shared__ int h[128];
  if (threadIdx.x < 128) h[threadIdx.x] = 0;
  __syncthreads();
  int stride = gridDim.x * blockDim.x;
  for (int i = blockIdx.x * blockDim.x + threadIdx.x; i < E; i += stride)
    atomicAdd(&h[(et[i] & 7) * NG + (edst[i] >> 13)], 1);
  __syncthreads();
  if (threadIdx.x < 128) atomicAdd(&gh[threadIdx.x], h[threadIdx.x]);
}

__global__ void k_cscan(const int* __restrict__ gh, int* __restrict__ gcursor,
                        int* __restrict__ cbase, int NBC, int E) {
  if (threadIdx.x == 0) {
    int a = 0;
    for (int b = 0; b < NBC; ++b) { cbase[b] = a; gcursor[b] = a; a += gh[b]; }
    cbase[NBC] = E;
  }
}

// per-block bulk reservation: each block owns a contiguous edge slice; writes its
// edges into private contiguous sub-segments per bin -> L2 write-back merges.
__launch_bounds__(256)
__global__ void k_cfill(const int* __restrict__ et, const int* __restrict__ esrc,
                        const int* __restrict__ edst, int* __restrict__ gcursor,
                        int* __restrict__ stage, int NG, int E) {
  __shared__ int h[128], base[128], lc[128];
  int nb = gridDim.x;
  int slice = (E + nb - 1) / nb;
  int lo = blockIdx.x * slice;
  int hi = lo + slice < E ? lo + slice : E;
  int t = threadIdx.x;
  if (t < 128) { h[t] = 0; lc[t] = 0; }
  __syncthreads();
  for (int i = lo + t; i < hi; i += 256)
    atomicAdd(&h[(et[i] & 7) * NG + (edst[i] >> 13)], 1);
  __syncthreads();
  if (t < 128 && h[t] > 0) base[t] = atomicAdd(&gcursor[t], h[t]);
  __syncthreads();
  for (int i = lo + t; i < hi; i += 256) {
    int d = edst[i];
    int tile = d >> 6;
    int bin = (et[i] & 7) * NG + (tile >> 7);
    int p = base[bin] + atomicAdd(&lc[bin], 1);
    stage[p] = ((tile & 127) << 23) | ((d & 63) << 17) | esrc[i];
  }
}

// one block per coarse bin: in-LDS counting sort over 8192 (tilelow,row) keys.
// Outputs srcl grouped by (rel,d) and rel-major lo9/len9 [r*NTr + d].
__launch_bounds__(1024)
__global__ void k_fine(const int* __restrict__ cbase, const int* __restrict__ stage,
                       int* __restrict__ srcl, int* __restrict__ lo9,
                       int* __restrict__ len9, int NG, int NTr) {
  __shared__ int h[8192];
  __shared__ int tsum[1024];
  __shared__ int wsum[16];
  int b = blockIdx.x;
  int rel = b / NG, tg = b - rel * NG;
  int lo = cbase[b], hi = cbase[b + 1];
  int t = threadIdx.x;
  for (int k = t; k < 8192; k += 1024) h[k] = 0;
  __syncthreads();
  for (int i = lo + t; i < hi; i += 1024)
    atomicAdd(&h[(stage[i] >> 17) & 0x1FFF], 1);
  __syncthreads();
  int dbase = tg * 8192;
  size_t relbase = (size_t)rel * NTr;
  for (int k = t; k < 8192; k += 1024) {
    int d = dbase + k;
    if (d < NTr) len9[relbase + d] = h[k];
  }
  // hierarchical exclusive scan of h[8192]: 8/thread serial, wave shfl, 16 waves
  int loc[8];
  int s = 0;
  int kb = t * 8;
#pragma unroll
  for (int j = 0; j < 8; ++j) { loc[j] = s; s += h[kb + j]; }
  tsum[t] = s;
  __syncthreads();
  int lane = t & 63, w = t >> 6;
  int v = tsum[t];
#pragma unroll
  for (int o = 1; o < 64; o <<= 1) {
    int u = __shfl_up(v, o);
    if (lane >= o) v += u;
  }
  if (lane == 63) wsum[w] = v;
  __syncthreads();
  if (t == 0) {
    int a = 0;
#pragma unroll
    for (int j = 0; j < 16; ++j) { int tmp = wsum[j]; wsum[j] = a; a += tmp; }
  }
  __syncthreads();
  int texcl = v - s + wsum[w];
#pragma unroll
  for (int j = 0; j < 8; ++j) h[kb + j] = texcl + loc[j];
  __syncthreads();
  for (int k = t; k < 8192; k += 1024) {
    int d = dbase + k;
    if (d < NTr) lo9[relbase + d] = lo + h[k];
  }
  __syncthreads();
  for (int i = lo + t; i < hi; i += 1024) {
    int pk = stage[i];
    int key = (pk >> 17) & 0x1FFF;
    int p = atomicAdd(&h[key], 1);
    srcl[lo + p] = pk & 0x1FFFF;
  }
}

// ---------------- weight prep: fp32 [9][128][DOUT] -> bf16 [9][DOUT][128] ----------------

__global__ void wprep_kernel(const float* __restrict__ Wrel, const float* __restrict__ Wroot,
                             unsigned short* __restrict__ wt, int DOUT) {
  int total = 9 * 128 * DOUT;
  int stride = gridDim.x * blockDim.x;
  for (int i = blockIdx.x * blockDim.x + threadIdx.x; i < total; i += stride) {
    int k = i & 127;
    int oo = i >> 7;
    int o = oo % DOUT;
    int rr = oo / DOUT;
    float v = (rr < 8) ? Wrel[((size_t)rr * 128 + k) * DOUT + o]
                       : Wroot[(size_t)k * DOUT + o];
    wt[i] = f2b(v);
  }
}

// ---------------- aggregation: Y slice j = sum over seg(r0+j, d) of x[src] ----

template <int NRP>
__launch_bounds__(256)
__global__ void agg_kernel(const unsigned* __restrict__ x32,   // [NTr][64] dwords
                           const int* __restrict__ lo9, const int* __restrict__ len9,
                           const int* __restrict__ srcl,
                           unsigned* __restrict__ Ydw,         // [NTr][NRP*64] dwords
                           int r0, int N, int E, int NTr) {
  int lane = threadIdx.x & 63;
  int d = (blockIdx.x * blockDim.x + threadIdx.x) >> 6;
  if (d >= N) return;

  int lo[NRP], ln[NRP];
#pragma unroll
  for (int r = 0; r < NRP; ++r) {
    size_t idx = (size_t)(r0 + r) * NTr + d;
    lo[r] = lo9[idx];
    ln[r] = len9[idx];
  }

  int s0[NRP], s1[NRP];
#pragma unroll
  for (int r = 0; r < NRP; ++r) {
    s0[r] = srcl[imin(lo[r], E - 1)];
    s1[r] = srcl[imin(lo[r] + 1, E - 1)];
  }
  unsigned v0[NRP], v1[NRP];
#pragma unroll
  for (int r = 0; r < NRP; ++r) {
    v0[r] = x32[(size_t)s0[r] * 64 + lane];
    v1[r] = x32[(size_t)s1[r] * 64 + lane];
  }

#pragma unroll
  for (int r = 0; r < NRP; ++r) {
    float a0 = 0.f, a1 = 0.f;
    if (ln[r] > 0) { a0 += lo16f(v0[r]); a1 += hi16f(v0[r]); }
    if (ln[r] > 1) { a0 += lo16f(v1[r]); a1 += hi16f(v1[r]); }
    if (ln[r] > 2) {
      int i = lo[r] + 2, e = lo[r] + ln[r];
      for (; i + 2 <= e; i += 2) {
        int sA = srcl[i], sB = srcl[i + 1];
        unsigned vA = x32[(size_t)sA * 64 + lane];
        unsigned vB = x32[(size_t)sB * 64 + lane];
        a0 += lo16f(vA) + lo16f(vB);
        a1 += hi16f(vA) + hi16f(vB);
      }
      if (i < e) {
        unsigned vA = x32[(size_t)srcl[i] * 64 + lane];
        a0 += lo16f(vA);
        a1 += hi16f(vA);
      }
    }
    Ydw[(size_t)d * (NRP * 64) + r * 64 + lane] =
        (unsigned)f2b(a0) | ((unsigned)f2b(a1) << 16);
  }
}

// ---------------- LDS-staged GEMM, col-split waves: acc = sum_t A_t @ W_t -------

struct SrcArr {
  const unsigned short* a[9];
  const unsigned short* w[9];
  int st[9];
};

// EPI: 0=bias->bf16; 1=partial+relu->bf16; 2=partial+lsm->f32;
//      3=bias+relu->bf16; 4=bias+lsm->f32; 5=partial->bf16
template <int DOUT, int NK, int EPI>
__launch_bounds__(256)
__global__ void gemm_lds(SrcArr S, const float* __restrict__ bias,
                         const unsigned short* __restrict__ part,
                         unsigned short* __restrict__ out_b,
                         float* __restrict__ out_f, int N) {
  __shared__ unsigned short Al[2][64 * 128];
  constexpr int NF = (DOUT == 128) ? 2 : 1;
  int tid = threadIdx.x, wid = tid >> 6, lane = tid & 63;
  int colb = lane & 15, kgrp = lane >> 4;
  int colw = wid * 16 * NF;
  int tilebase = blockIdx.x * 64;

  auto stage = [&](int t, int buf) {
    const unsigned short* sa = S.a[t] + (size_t)tilebase * S.st[t];
    int st = S.st[t];
#pragma unroll
    for (int q = 0; q < 4; ++q) {
      int c = q * 256 + tid;
      int row = c >> 4, kcl = c & 15;
      int kcg = kcl ^ (row & 7);
      const unsigned short* gp = sa + (size_t)row * st + kcg * 8;
      unsigned short* lp = &Al[buf][(q * 256 + (tid & ~63)) * 8];
      __builtin_amdgcn_global_load_lds(
          (__attribute__((address_space(1))) void*)gp,
          (__attribute__((address_space(3))) void*)lp, 16, 0, 0);
    }
  };

  f32x4 acc[4][NF];
#pragma unroll
  for (int rb = 0; rb < 4; ++rb)
#pragma unroll
    for (int nf = 0; nf < NF; ++nf) {
      f32x4 z = {0.f, 0.f, 0.f, 0.f};
      acc[rb][nf] = z;
    }

  stage(0, 0);
#pragma unroll
  for (int t = 0; t < NK; ++t) {
    __syncthreads();
    if (t + 1 < NK) stage(t + 1, (t + 1) & 1);
    const unsigned short* W = S.w[t];
    const unsigned short* Ab = Al[t & 1];
#pragma unroll
    for (int kk = 0; kk < 4; ++kk) {
      int kc = kk * 4 + kgrp;
      bf16x8 a[4];
#pragma unroll
      for (int rb = 0; rb < 4; ++rb) {
        int arow = rb * 16 + colb;
        a[rb] = *(const bf16x8*)(Ab + (size_t)(arow * 16 + (kc ^ (arow & 7))) * 8);
      }
#pragma unroll
      for (int nf = 0; nf < NF; ++nf) {
        bf16x8 b = *(const bf16x8*)(W + (size_t)(colw + nf * 16 + colb) * 128 + kc * 8);
#pragma unroll
        for (int rb = 0; rb < 4; ++rb)
          acc[rb][nf] = __builtin_amdgcn_mfma_f32_16x16x32_bf16(a[rb], b, acc[rb][nf], 0, 0, 0);
      }
    }
  }

  float bv[NF];
  if (EPI == 0 || EPI == 3 || EPI == 4) {
#pragma unroll
    for (int nf = 0; nf < NF; ++nf) bv[nf] = bias[colw + nf * 16 + colb];
  }

  if ((EPI == 2 || EPI == 4) && DOUT == 64) {
    float* Lf = (float*)Al;       // [64][68] padded
    __syncthreads();
#pragma unroll
    for (int rb = 0; rb < 4; ++rb)
#pragma unroll
      for (int i = 0; i < 4; ++i) {
        int row = rb * 16 + kgrp * 4 + i;
        int grow = tilebase + row;
        int rc = grow < N ? grow : 0;
        float v = acc[rb][0][i];
        if (EPI == 4) v += bv[0];
        else v += b2f(part[(size_t)rc * 64 + colw + colb]);
        Lf[row * 68 + colw + colb] = v;
      }
    __syncthreads();
#pragma unroll
    for (int it = 0; it < 4; ++it) {
      int row = wid * 16 + it * 4 + (lane >> 4);
      float v[4];
#pragma unroll
      for (int j = 0; j < 4; ++j) v[j] = Lf[row * 68 + colb + j * 16];
      float m = fmaxf(fmaxf(v[0], v[1]), fmaxf(v[2], v[3]));
#pragma unroll
      for (int s = 1; s < 16; s <<= 1) m = fmaxf(m, __shfl_xor(m, s));
      float sum = 0.f;
#pragma unroll
      for (int j = 0; j < 4; ++j) sum += __expf(v[j] - m);
#pragma unroll
      for (int s = 1; s < 16; s <<= 1) sum += __shfl_xor(sum, s);
      float lse = m + __logf(sum);
      int grow = tilebase + row;
      if (grow < N) {
#pragma unroll
        for (int j = 0; j < 4; ++j)
          out_f[(size_t)grow * 64 + colb + j * 16] = v[j] - lse;
      }
    }
  } else {
#pragma unroll
    for (int rb = 0; rb < 4; ++rb)
#pragma unroll
      for (int i = 0; i < 4; ++i) {
        int row = tilebase + rb * 16 + kgrp * 4 + i;
        bool ok = row < N;
        int rc = ok ? row : 0;
#pragma unroll
        for (int nf = 0; nf < NF; ++nf) {
          int col = colw + nf * 16 + colb;
          float v = acc[rb][nf][i];
          if (EPI == 0 || EPI == 3) v += bv[nf];
          if (EPI == 1 || EPI == 5) v += b2f(part[(size_t)rc * DOUT + col]);
          if (EPI == 1 || EPI == 3) v = fmaxf(v, 0.f);
          if (ok) out_b[(size_t)row * DOUT + col] = f2b(v);
        }
      }
  }
}

template <int DOUT>
static void run_gemm(int NK, int EPI, const SrcArr& S, const float* bias,
                     const unsigned short* part, unsigned short* ob, float* of,
                     int N, int NT, hipStream_t st) {
#define GCALL(nk, epi)                                                        \
  if (NK == nk && EPI == epi) {                                               \
    gemm_lds<DOUT, nk, epi><<<NT, 256, 0, st>>>(S, bias, part, ob, of, N);    \
    return;                                                                   \
  }
  GCALL(9, 3) GCALL(9, 4)
  GCALL(5, 0) GCALL(4, 1) GCALL(4, 2)
  GCALL(3, 0) GCALL(2, 5) GCALL(2, 1) GCALL(2, 2)
#undef GCALL
}

// ---------------- input cast ----------------

__global__ void cast_kernel(const float* __restrict__ in, unsigned short* __restrict__ out,
                            int n4) {
  int stride = gridDim.x * blockDim.x;
  for (int i = blockIdx.x * blockDim.x + threadIdx.x; i < n4; i += stride) {
    float4 v = ((const float4*)in)[i];
    ushort4 o;
    o.x = f2b(v.x); o.y = f2b(v.y); o.z = f2b(v.z); o.w = f2b(v.w);
    ((ushort4*)out)[i] = o;
  }
}

// ---------------- launch ----------------

extern "C" void kernel_launch(void* const* d_in, const int* in_sizes, int n_in,
                              void* d_out, int out_size, void* d_ws, size_t ws_size,
                              hipStream_t stream) {
  const float* x = (const float*)d_in[0];
  const int* eidx = (const int*)d_in[1];
  const int* et = (const int*)d_in[2];
  const float* Wrel1 = (const float*)d_in[3];
  const float* Wroot1 = (const float*)d_in[4];
  const float* b1 = (const float*)d_in[5];
  const float* Wrel2 = (const float*)d_in[6];
  const float* Wroot2 = (const float*)d_in[7];
  const float* b2 = (const float*)d_in[8];
  const float* Wrel3 = (const float*)d_in[9];
  const float* Wroot3 = (const float*)d_in[10];
  const float* b3 = (const float*)d_in[11];

  const int N = in_sizes[0] / 128;    // 100000
  const int E = in_sizes[2];          // 1600000
  const int NT = (N + 63) / 64;       // 1563
  const int NTr = NT * 64;            // 100032
  const int NG = (NT + 127) / 128;    // 13 tile-groups of 128
  const int NBC = 8 * NG;             // 104 coarse bins
  const int* esrc = eidx;
  const int* edst = eidx + E;

  const size_t XB = (size_t)NTr * 128 * 2;   // 25.6 MB

  size_t fixedB = 2 * XB + 2 * ((size_t)9 * 128 * 128 * 2) + (size_t)9 * 64 * 128 * 2 +
                  2 * ((size_t)E * 4) + 2 * ((size_t)8 * NTr * 4) + 4096 + 16 * 256;
  int NRP = 8;
  if (fixedB + 8 * XB > ws_size) NRP = 4;
  if (NRP == 4 && fixedB + 4 * XB + XB > ws_size) NRP = 2;

  char* p = (char*)d_ws;
  auto carve = [&](size_t bytes) {
    void* q = (void*)p;
    p += (bytes + 255) & ~(size_t)255;
    return q;
  };
  unsigned short* bufX0 = (unsigned short*)carve(XB);
  unsigned short* bufX1 = (unsigned short*)carve(XB);
  unsigned short* wt1 = (unsigned short*)carve((size_t)9 * 128 * 128 * 2);
  unsigned short* wt2 = (unsigned short*)carve((size_t)9 * 128 * 128 * 2);
  unsigned short* wt3 = (unsigned short*)carve((size_t)9 * 64 * 128 * 2);
  int* stage = (int*)carve((size_t)E * 4);
  int* srcl = (int*)carve((size_t)E * 4);
  int* lo9 = (int*)carve((size_t)8 * NTr * 4);
  int* len9 = (int*)carve((size_t)8 * NTr * 4);
  int* gh = (int*)carve(512);
  int* gcursor = (int*)carve(512);
  int* cbase = (int*)carve(512);
  unsigned short* part = (unsigned short*)((NRP < 8) ? carve(XB) : nullptr);
  unsigned short* Y = (unsigned short*)carve((size_t)NRP * XB);

  // ---- sort v5 (once; reused by all 3 layers) ----
  k_zero2<<<1, 128, 0, stream>>>(gh, 128);
  k_chist<<<512, 256, 0, stream>>>(et, edst, gh, NG, E);
  k_cscan<<<1, 64, 0, stream>>>(gh, gcursor, cbase, NBC, E);
  k_cfill<<<512, 256, 0, stream>>>(et, esrc, edst, gcursor, stage, NG, E);
  k_fine<<<NBC, 1024, 0, stream>>>(cbase, stage, srcl, lo9, len9, NG, NTr);

  // ---- weight prep + input cast ----
  wprep_kernel<<<576, 256, 0, stream>>>(Wrel1, Wroot1, wt1, 128);
  wprep_kernel<<<576, 256, 0, stream>>>(Wrel2, Wroot2, wt2, 128);
  wprep_kernel<<<288, 256, 0, stream>>>(Wrel3, Wroot3, wt3, 64);
  cast_kernel<<<2048, 256, 0, stream>>>(x, bufX0, N * 128 / 4);

  const int ablk = (N * 64 + 255) / 256;
  const int passes = 8 / NRP;

  auto layer = [&](const unsigned short* xin, const unsigned short* wt,
                   const float* bias, int DOUT, unsigned short* xout, float* fout) {
    for (int pidx = 0; pidx < passes; ++pidx) {
      int r0 = pidx * NRP;
      if (NRP == 8)
        agg_kernel<8><<<ablk, 256, 0, stream>>>((const unsigned*)xin, lo9, len9, srcl, (unsigned*)Y, r0, N, E, NTr);
      else if (NRP == 4)
        agg_kernel<4><<<ablk, 256, 0, stream>>>((const unsigned*)xin, lo9, len9, srcl, (unsigned*)Y, r0, N, E, NTr);
      else
        agg_kernel<2><<<ablk, 256, 0, stream>>>((const unsigned*)xin, lo9, len9, srcl, (unsigned*)Y, r0, N, E, NTr);

      SrcArr S;
      int idx = 0;
      if (pidx == 0) {
        S.a[0] = xin; S.w[0] = wt + (size_t)8 * DOUT * 128; S.st[0] = 128;
        idx = 1;
      }
      for (int j = 0; j < NRP; ++j) {
        S.a[idx] = Y + j * 128;
        S.w[idx] = wt + (size_t)(r0 + j) * DOUT * 128;
        S.st[idx] = NRP * 128;
        ++idx;
      }
      int NK = idx;
      int epi;
      bool lastp = (pidx == passes - 1);
      if (pidx == 0 && lastp) epi = (DOUT == 64) ? 4 : 3;
      else if (pidx == 0) epi = 0;
      else if (!lastp) epi = 5;
      else epi = (DOUT == 64) ? 2 : 1;

      unsigned short* ob = lastp ? xout : part;
      if (pidx == 0 && !lastp) ob = part;
      if (DOUT == 128)
        run_gemm<128>(NK, epi, S, bias, part, ob, fout, N, NT, stream);
      else
        run_gemm<64>(NK, epi, S, bias, part, ob, fout, N, NT, stream);
    }
  };

  layer(bufX0, wt1, b1, 128, bufX1, nullptr);
  layer(bufX1, wt2, b2, 128, bufX0, nullptr);
  layer(bufX0, wt3, b3, 64, nullptr, (float*)d_out);
}